// Round 5
// baseline (423.611 us; speedup 1.0000x reference)
//
#include <hip/hip_runtime.h>

// ---------------------------------------------------------------------------
// MLP-GNN fused op for MI355X (gfx950).
//   v  = tanh(tanh(z @ cw1^T + cb1) @ cw2^T + cb2)                    [N,128]
//   vn = tanh(tanh([z|z_] @ nw1^T + nb1) @ nw2^T + nb2).sum(axis=K)   [N,128]
//   dc = [v | vn] @ ow^T + ob                                         [N,64]
// R5 restructure: nbr_kernel = fully INDEPENDENT WAVES (zero barriers).
//   Each wave processes one n end-to-end:
//     z_ tile (32x128 f32) -> MFMA A-frags DIRECTLY from global (no staging)
//     weights from frag-linear bf16 arrays (prep_kernel; L1/L2-resident)
//     L1 tanh -> wave-private LDS scratch in L2-A-frag layout (no barrier;
//     per-wave DS ops are in-order) -> L2 -> k-sum via 2x shfl_xor -> feat.
//   128-thr blocks, launch_bounds(128,3) -> ~12 independent waves/CU.
// cur_kernel: v -> feat[:,0:128] AND u1 = z@nw1[:,:128]^T + nb1 (hoisted
// z-half of the neighbor concat). out_kernel: dc -> d_out.
// ---------------------------------------------------------------------------

typedef __bf16 bf16;
typedef __bf16 bf16x2 __attribute__((ext_vector_type(2)));
typedef __bf16 bf16x8 __attribute__((ext_vector_type(8)));
typedef float  f32x4  __attribute__((ext_vector_type(4)));

#define MFMA(a, b, c) __builtin_amdgcn_mfma_f32_16x16x32_bf16((a), (b), (c), 0, 0, 0)

#define C2LOG2E 2.885390081777927f   // 2*log2(e)

// tanh(x) = 1 - 2/(exp2(2*log2e*x)+1) — all signs, inf-safe.
__device__ __forceinline__ float fast_tanh(float x) {
    float t = __builtin_amdgcn_exp2f(x * C2LOG2E);
    return 1.0f - 2.0f * __builtin_amdgcn_rcpf(t + 1.0f);
}
// tanh(acc + u) with pre-scaled bias uc = u*C2LOG2E.
__device__ __forceinline__ float fast_tanh_fb(float acc, float uc) {
    float t = __builtin_amdgcn_exp2f(__builtin_fmaf(acc, C2LOG2E, uc));
    return 1.0f - 2.0f * __builtin_amdgcn_rcpf(t + 1.0f);
}
// r-part only: rcp(exp2(fma)+1); caller uses sum = count - 2*sum(r).
__device__ __forceinline__ float tanh_rpart(float acc, float uc) {
    float t = __builtin_amdgcn_exp2f(__builtin_fmaf(acc, C2LOG2E, uc));
    return __builtin_amdgcn_rcpf(t + 1.0f);
}

__device__ __forceinline__ bf16x8 cvt8(f32x4 a, f32x4 b) {
    bf16x8 r;
    r[0] = (bf16)a[0]; r[1] = (bf16)a[1]; r[2] = (bf16)a[2]; r[3] = (bf16)a[3];
    r[4] = (bf16)b[0]; r[5] = (bf16)b[1]; r[6] = (bf16)b[2]; r[7] = (bf16)b[3];
    return r;
}

// LDS tiles: 128-bf16 rows (256 B = 16 chunks), chunk-XOR swizzle (cur/out).
__device__ __forceinline__ int swz128(int row, int col) {
    int c = (col >> 3) ^ (row & 15);
    return row * 256 + c * 16 + (col & 7) * 2;
}
__device__ __forceinline__ int swz256(int row, int col) {
    int c = (col >> 3) ^ (row & 15);
    return row * 512 + c * 16 + (col & 7) * 2;
}

__device__ __forceinline__ void st_pair(char* base, int off, float a, float b) {
    bf16x2 p = {(bf16)a, (bf16)b};
    *(bf16x2*)(base + off) = p;
}

// ---------------------------------------------------------------------------
// prep_kernel: weights -> fragment-linear bf16 (one coalesced 16B load/tile
// in nbr). pw1 tile (kb,ht): lane l holds w1[ht*16+(l&15)][128+kb*32+(l>>4)*8+j].
// pw2 tile (kbh,ot): lane l holds w2[ot*16+(l&15)][kbh*32+(l>>4)*8+j].
// ---------------------------------------------------------------------------
__global__ void prep_kernel(const float* __restrict__ w1,
                            const float* __restrict__ w2,
                            bf16* __restrict__ pw1, bf16* __restrict__ pw2) {
    int s = blockIdx.x * blockDim.x + threadIdx.x;   // 0..2047
    int lane = s & 63, tile = s >> 6;                // tile 0..31
    int li = lane & 15, g = lane >> 4;
    {
        int kb = tile >> 3, ht = tile & 7;
        const float* src = w1 + (size_t)(ht * 16 + li) * 256 + 128 + kb * 32 + g * 8;
        bf16x8 v;
#pragma unroll
        for (int j = 0; j < 8; ++j) v[j] = (bf16)src[j];
        *(bf16x8*)(pw1 + (size_t)s * 8) = v;
    }
    {
        int kbh = tile >> 3, ot = tile & 7;
        const float* src = w2 + (size_t)(ot * 16 + li) * 128 + kbh * 32 + g * 8;
        bf16x8 v;
#pragma unroll
        for (int j = 0; j < 8; ++j) v[j] = (bf16)src[j];
        *(bf16x8*)(pw2 + (size_t)s * 8) = v;
    }
}

// ---------------------------------------------------------------------------
// nbr_kernel: independent waves, one n per wave per loop trip. No barriers.
// ---------------------------------------------------------------------------
__global__ __launch_bounds__(128, 3) void nbr_kernel(
    const float* __restrict__ zn, const float* __restrict__ u1f,
    const bf16* __restrict__ pw1, const bf16* __restrict__ pw2,
    const float* __restrict__ b2, bf16* __restrict__ feat, int N)
{
    __shared__ char lds[2][8192];   // wave-private a1 scratch (L2 A-frag layout)

    const int t = threadIdx.x, w = t >> 6, lane = t & 63;
    const int li = lane & 15, g = lane >> 4;
    char* aflds = lds[w];

    // pre-scaled L2 bias per ot (kernel-lifetime, 8 VGPRs)
    float bc2[8];
#pragma unroll
    for (int ot = 0; ot < 8; ++ot) bc2[ot] = b2[ot * 16 + li] * C2LOG2E;

    const int totWaves = gridDim.x * 2;
    const f32x4 vzero = {0.f, 0.f, 0.f, 0.f};

    for (int n = blockIdx.x * 2 + w; n < N; n += totWaves) {
        // ---- phase A: issue all z_ loads for this n (A-frag direct) ----
        f32x4 zf[2][4][2];   // [mt][kb][half]
#pragma unroll
        for (int mt = 0; mt < 2; ++mt)
#pragma unroll
            for (int kb = 0; kb < 4; ++kb) {
                const float* src = zn + ((size_t)n * 32 + 16 * mt + li) * 128 + kb * 32 + g * 8;
                zf[mt][kb][0] = *(const f32x4*)(src);
                zf[mt][kb][1] = *(const f32x4*)(src + 4);
            }
        float uc[8];   // u1 bias (z-half of L1), pre-scaled
#pragma unroll
        for (int ht = 0; ht < 8; ++ht)
            uc[ht] = u1f[(size_t)n * 128 + ht * 16 + li] * C2LOG2E;

        // ---- L1: D1[m][h] over z_-half, weights streamed from pw1 ----
        f32x4 acc1[2][8];
#pragma unroll
        for (int mt = 0; mt < 2; ++mt)
#pragma unroll
            for (int ht = 0; ht < 8; ++ht) acc1[mt][ht] = vzero;

#pragma unroll
        for (int kb = 0; kb < 4; ++kb) {
            bf16x8 az0 = cvt8(zf[0][kb][0], zf[0][kb][1]);
            bf16x8 az1 = cvt8(zf[1][kb][0], zf[1][kb][1]);
#pragma unroll
            for (int ht = 0; ht < 8; ++ht) {
                bf16x8 wf = *(const bf16x8*)(pw1 + (size_t)((kb * 8 + ht) * 64 + lane) * 8);
                acc1[0][ht] = MFMA(az0, wf, acc1[0][ht]);
                acc1[1][ht] = MFMA(az1, wf, acc1[1][ht]);
            }
        }

        // ---- phase B: tanh(acc1 + u1) -> wave-private LDS (L2 A-frag) ----
        // value (mt,ht,r): m = mt*16 + g*4 + r, h = ht*16 + li.
        // consumer frag (mt*4 + ht>>1), lane lc = ((ht&1)*2 + (li>>3))*16 + g*4 + r,
        // j = li&7  ->  byte = (frag*64 + lc)*16 + j*2.
#pragma unroll
        for (int mt = 0; mt < 2; ++mt)
#pragma unroll
            for (int ht = 0; ht < 8; ++ht) {
                int fragbase = ((mt * 4 + (ht >> 1)) * 64 + ((ht & 1) * 2 + (li >> 3)) * 16 + g * 4) * 16
                               + (li & 7) * 2;
#pragma unroll
                for (int r = 0; r < 4; ++r) {
                    float v = fast_tanh_fb(acc1[mt][ht][r], uc[ht]);
                    *(bf16*)(aflds + fragbase + r * 16) = (bf16)v;
                }
            }

        // ---- L2: D2[m][o], a1 from LDS frags, weights from pw2 ----
        f32x4 acc2[2][8];
#pragma unroll
        for (int mt = 0; mt < 2; ++mt)
#pragma unroll
            for (int ot = 0; ot < 8; ++ot) acc2[mt][ot] = vzero;

#pragma unroll
        for (int kbh = 0; kbh < 4; ++kbh) {
            bf16x8 a0 = *(const bf16x8*)(aflds + (size_t)((0 + kbh) * 64 + lane) * 16);
            bf16x8 a1 = *(const bf16x8*)(aflds + (size_t)((4 + kbh) * 64 + lane) * 16);
#pragma unroll
            for (int ot = 0; ot < 8; ++ot) {
                bf16x8 wf = *(const bf16x8*)(pw2 + (size_t)((kbh * 8 + ot) * 64 + lane) * 8);
                acc2[0][ot] = MFMA(a0, wf, acc2[0][ot]);
                acc2[1][ot] = MFMA(a1, wf, acc2[1][ot]);
            }
        }

        // ---- phase D: k-sum of tanh over 32 rows = 32 - 2*sum(rpart) ----
#pragma unroll
        for (int ot = 0; ot < 8; ++ot) {
            float s = 0.f;
#pragma unroll
            for (int mt = 0; mt < 2; ++mt)
#pragma unroll
                for (int r = 0; r < 4; ++r)
                    s += tanh_rpart(acc2[mt][ot][r], bc2[ot]);
            s += __shfl_xor(s, 16);
            s += __shfl_xor(s, 32);
            if (lane < 16) {
                float v = __builtin_fmaf(-2.f, s, 32.f);
                feat[(size_t)n * 256 + 128 + ot * 16 + li] = (bf16)v;
            }
        }
    }
}

// ---------------------------------------------------------------------------
// Kernel A: cur branch (feat[:,0:128]) + u1 = z @ nw1[:,:128]^T + nb1.
// ---------------------------------------------------------------------------
__global__ __launch_bounds__(256, 2) void cur_kernel(
    const float* __restrict__ z,
    const float* __restrict__ w1, const float* __restrict__ b1,
    const float* __restrict__ w2, const float* __restrict__ b2,
    const float* __restrict__ nw1, const float* __restrict__ nb1,
    bf16* __restrict__ feat, float* __restrict__ u1, int N)
{
    __shared__ char z_lds[64 * 256];
    __shared__ char h1_lds[64 * 256];

    const int t = threadIdx.x;
    const int wv = t >> 6, lane = t & 63, g = lane >> 4, li = lane & 15;
    const int hbase = wv * 32;
    const int n0 = blockIdx.x * 64;

    bf16x8 w1f[2][4], w2f[2][4], wzf[2][4];
#pragma unroll
    for (int ht = 0; ht < 2; ++ht)
#pragma unroll
        for (int kb = 0; kb < 4; ++kb) {
            const float* p1 = w1 + (size_t)(hbase + 16*ht + li) * 128 + kb*32 + 8*g;
            w1f[ht][kb] = cvt8(*(const f32x4*)p1, *(const f32x4*)(p1 + 4));
            const float* p2 = w2 + (size_t)(hbase + 16*ht + li) * 128 + kb*32 + 8*g;
            w2f[ht][kb] = cvt8(*(const f32x4*)p2, *(const f32x4*)(p2 + 4));
            const float* p3 = nw1 + (size_t)(hbase + 16*ht + li) * 256 + kb*32 + 8*g;
            wzf[ht][kb] = cvt8(*(const f32x4*)p3, *(const f32x4*)(p3 + 4));
        }
    float b1v[2][4], b2v[2][4], bnv[2][4];
#pragma unroll
    for (int ht = 0; ht < 2; ++ht)
#pragma unroll
        for (int rr = 0; rr < 4; ++rr) {
            b1v[ht][rr] = b1[hbase + 16*ht + 4*g + rr];
            b2v[ht][rr] = b2[hbase + 16*ht + 4*g + rr];
            bnv[ht][rr] = nb1[hbase + 16*ht + 4*g + rr];
        }

    {
        int m = t >> 2;
        int c0 = (t & 3) * 32;
        int row = n0 + m; if (row > N - 1) row = N - 1;
        const float* src = z + (size_t)row * 128 + c0;
#pragma unroll
        for (int q = 0; q < 4; ++q) {
            f32x4 a = *(const f32x4*)(src + 8*q);
            f32x4 b = *(const f32x4*)(src + 8*q + 4);
            *(bf16x8*)(z_lds + swz128(m, c0 + 8*q)) = cvt8(a, b);
        }
    }
    __syncthreads();

    const f32x4 vzero = {0.f, 0.f, 0.f, 0.f};
    f32x4 acc1[2][4], accz[2][4];
#pragma unroll
    for (int a = 0; a < 2; ++a)
#pragma unroll
        for (int b = 0; b < 4; ++b) { acc1[a][b] = vzero; accz[a][b] = vzero; }

#pragma unroll
    for (int kb = 0; kb < 4; ++kb) {
        bf16x8 bz[4];
#pragma unroll
        for (int mt = 0; mt < 4; ++mt)
            bz[mt] = *(const bf16x8*)(z_lds + swz128(16*mt + li, kb*32 + 8*g));
#pragma unroll
        for (int ht = 0; ht < 2; ++ht)
#pragma unroll
            for (int mt = 0; mt < 4; ++mt) {
                acc1[ht][mt] = MFMA(w1f[ht][kb], bz[mt], acc1[ht][mt]);
                accz[ht][mt] = MFMA(wzf[ht][kb], bz[mt], accz[ht][mt]);
            }
    }

#pragma unroll
    for (int ht = 0; ht < 2; ++ht)
#pragma unroll
        for (int mt = 0; mt < 4; ++mt) {
            int row = n0 + 16*mt + li;
            if (row < N) {
                f32x4 v;
#pragma unroll
                for (int rr = 0; rr < 4; ++rr) v[rr] = accz[ht][mt][rr] + bnv[ht][rr];
                *(f32x4*)(u1 + (size_t)row * 128 + hbase + 16*ht + 4*g) = v;
            }
        }

#pragma unroll
    for (int ht = 0; ht < 2; ++ht)
#pragma unroll
        for (int mt = 0; mt < 4; ++mt) {
            float v0 = fast_tanh(acc1[ht][mt][0] + b1v[ht][0]);
            float v1 = fast_tanh(acc1[ht][mt][1] + b1v[ht][1]);
            float v2 = fast_tanh(acc1[ht][mt][2] + b1v[ht][2]);
            float v3 = fast_tanh(acc1[ht][mt][3] + b1v[ht][3]);
            int m = 16*mt + li;
            int h = hbase + 16*ht + 4*g;
            st_pair(h1_lds, swz128(m, h),     v0, v1);
            st_pair(h1_lds, swz128(m, h + 2), v2, v3);
        }
    __syncthreads();

    f32x4 acc2[2][4];
#pragma unroll
    for (int a = 0; a < 2; ++a)
#pragma unroll
        for (int b = 0; b < 4; ++b) acc2[a][b] = vzero;

#pragma unroll
    for (int kb = 0; kb < 4; ++kb) {
        bf16x8 bh[4];
#pragma unroll
        for (int mt = 0; mt < 4; ++mt)
            bh[mt] = *(const bf16x8*)(h1_lds + swz128(16*mt + li, kb*32 + 8*g));
#pragma unroll
        for (int ht = 0; ht < 2; ++ht)
#pragma unroll
            for (int mt = 0; mt < 4; ++mt)
                acc2[ht][mt] = MFMA(w2f[ht][kb], bh[mt], acc2[ht][mt]);
    }
#pragma unroll
    for (int ht = 0; ht < 2; ++ht)
#pragma unroll
        for (int mt = 0; mt < 4; ++mt) {
            float v0 = fast_tanh(acc2[ht][mt][0] + b2v[ht][0]);
            float v1 = fast_tanh(acc2[ht][mt][1] + b2v[ht][1]);
            float v2 = fast_tanh(acc2[ht][mt][2] + b2v[ht][2]);
            float v3 = fast_tanh(acc2[ht][mt][3] + b2v[ht][3]);
            int row = n0 + 16*mt + li;
            if (row < N) {
                int h = hbase + 16*ht + 4*g;
                bf16* dst = feat + (size_t)row * 256 + h;
                bf16x2 p01 = {(bf16)v0, (bf16)v1};
                bf16x2 p23 = {(bf16)v2, (bf16)v3};
                *(bf16x2*)(dst)     = p01;
                *(bf16x2*)(dst + 2) = p23;
            }
        }
}

// ---------------------------------------------------------------------------
// Kernel C: dc = feat[N,256] @ ow^T + ob -> f32 out. 64 rows/block.
// ---------------------------------------------------------------------------
__global__ __launch_bounds__(256, 2) void out_kernel(
    const bf16* __restrict__ feat,
    const float* __restrict__ ow, const float* __restrict__ ob,
    float* __restrict__ out, int N)
{
    __shared__ char f_lds[64 * 512];

    const int t = threadIdx.x, wv = t >> 6, lane = t & 63, g = lane >> 4, li = lane & 15;
    const int cbase = wv * 16;
    const int n0 = blockIdx.x * 64;

    bf16x8 owf[8];
#pragma unroll
    for (int kb = 0; kb < 8; ++kb) {
        const float* p = ow + (size_t)(cbase + li) * 256 + kb*32 + 8*g;
        owf[kb] = cvt8(*(const f32x4*)p, *(const f32x4*)(p + 4));
    }
    float obv = ob[cbase + li];

    {
        int m = t >> 2;
        int c0 = (t & 3) * 64;
        int row = n0 + m; if (row > N - 1) row = N - 1;
        const bf16* src = feat + (size_t)row * 256 + c0;
#pragma unroll
        for (int q = 0; q < 8; ++q)
            *(bf16x8*)(f_lds + swz256(m, c0 + 8*q)) = *(const bf16x8*)(src + 8*q);
    }
    __syncthreads();

    const f32x4 vzero = {0.f, 0.f, 0.f, 0.f};
    f32x4 acc[4];
#pragma unroll
    for (int a = 0; a < 4; ++a) acc[a] = vzero;

#pragma unroll
    for (int kb = 0; kb < 8; ++kb) {
        bf16x8 af[4];
#pragma unroll
        for (int mt = 0; mt < 4; ++mt)
            af[mt] = *(const bf16x8*)(f_lds + swz256(16*mt + li, kb*32 + 8*g));
#pragma unroll
        for (int mt = 0; mt < 4; ++mt)
            acc[mt] = MFMA(af[mt], owf[kb], acc[mt]);
    }
#pragma unroll
    for (int mt = 0; mt < 4; ++mt)
#pragma unroll
        for (int rr = 0; rr < 4; ++rr) {
            int row = n0 + 16*mt + 4*g + rr;
            if (row < N) out[(size_t)row * 64 + cbase + li] = acc[mt][rr] + obv;
        }
}

// ---------------------------------------------------------------------------
extern "C" void kernel_launch(void* const* d_in, const int* in_sizes, int n_in,
                              void* d_out, int out_size, void* d_ws, size_t ws_size,
                              hipStream_t stream) {
    const float* z   = (const float*)d_in[0];
    const float* zn  = (const float*)d_in[1];
    const float* cw1 = (const float*)d_in[2];
    const float* cb1 = (const float*)d_in[3];
    const float* cw2 = (const float*)d_in[4];
    const float* cb2 = (const float*)d_in[5];
    const float* nw1 = (const float*)d_in[6];
    const float* nb1 = (const float*)d_in[7];
    const float* nw2 = (const float*)d_in[8];
    const float* nb2 = (const float*)d_in[9];
    const float* ow  = (const float*)d_in[10];
    const float* ob  = (const float*)d_in[11];
    float* out = (float*)d_out;

    const int N = in_sizes[0] / 128;           // 20000
    const int nblk = (N + 63) / 64;            // 313

    char* ws = (char*)d_ws;
    bf16*  feat = (bf16*)ws;                                   // [N][256] bf16
    float* u1   = (float*)(ws + (size_t)N * 256 * sizeof(bf16)); // [N][128] f32
    bf16*  pw1  = (bf16*)(ws + (size_t)N * 256 * sizeof(bf16) + (size_t)N * 128 * sizeof(float));
    bf16*  pw2  = pw1 + 2048 * 8;              // 32 KB each

    (void)n_in; (void)out_size; (void)ws_size;

    prep_kernel<<<8, 256, 0, stream>>>(nw1, nw2, pw1, pw2);
    cur_kernel<<<nblk, 256, 0, stream>>>(z, cw1, cb1, cw2, cb2, nw1, nb1, feat, u1, N);
    nbr_kernel<<<1536, 128, 0, stream>>>(zn, u1, pw1, pw2, nb2, feat, N);
    out_kernel<<<nblk, 256, 0, stream>>>(feat, ow, ob, out, N);
}

// Round 6
// 355.615 us; speedup vs baseline: 1.1912x; 1.1912x over previous
//
#include <hip/hip_runtime.h>

// ---------------------------------------------------------------------------
// MLP-GNN fused op for MI355X (gfx950).
//   v  = tanh(tanh(z @ cw1^T + cb1) @ cw2^T + cb2)                    [N,128]
//   vn = tanh(tanh([z|z_] @ nw1^T + nb1) @ nw2^T + nb2).sum(axis=K)   [N,128]
//   dc = [v | vn] @ ow^T + ob                                         [N,64]
// nbr_kernel: fully independent waves (zero barriers), one n per wave trip:
//   z_ tile -> MFMA A-frags direct from global; weights streamed from
//   frag-linear bf16 arrays (prep_kernel, L2-resident); L1 tanh -> wave-
//   private LDS scratch (in-order DS, no barrier) -> L2 -> k-sum -> feat.
// R6 spill fix (R5 postmortem: launch_bounds(128,3) clamped VGPR to 84 ->
// zf spilled, 300 MB scratch writes): 256-thr blocks + launch_bounds(256,3)
// (documented k=3 blocks/CU, VGPR cap 170, 12 waves/CU) and early bf16
// conversion so peak live ~130 regs.
// ---------------------------------------------------------------------------

typedef __bf16 bf16;
typedef __bf16 bf16x2 __attribute__((ext_vector_type(2)));
typedef __bf16 bf16x8 __attribute__((ext_vector_type(8)));
typedef float  f32x4  __attribute__((ext_vector_type(4)));

#define MFMA(a, b, c) __builtin_amdgcn_mfma_f32_16x16x32_bf16((a), (b), (c), 0, 0, 0)

#define C2LOG2E 2.885390081777927f   // 2*log2(e)

// tanh(x) = 1 - 2/(exp2(2*log2e*x)+1) — all signs, inf-safe.
__device__ __forceinline__ float fast_tanh(float x) {
    float t = __builtin_amdgcn_exp2f(x * C2LOG2E);
    return 1.0f - 2.0f * __builtin_amdgcn_rcpf(t + 1.0f);
}
// tanh(acc + u) with pre-scaled bias uc = u*C2LOG2E.
__device__ __forceinline__ float fast_tanh_fb(float acc, float uc) {
    float t = __builtin_amdgcn_exp2f(__builtin_fmaf(acc, C2LOG2E, uc));
    return 1.0f - 2.0f * __builtin_amdgcn_rcpf(t + 1.0f);
}
// r-part only: rcp(exp2(fma)+1); caller uses sum = count - 2*sum(r).
__device__ __forceinline__ float tanh_rpart(float acc, float uc) {
    float t = __builtin_amdgcn_exp2f(__builtin_fmaf(acc, C2LOG2E, uc));
    return __builtin_amdgcn_rcpf(t + 1.0f);
}

__device__ __forceinline__ bf16x8 cvt8(f32x4 a, f32x4 b) {
    bf16x8 r;
    r[0] = (bf16)a[0]; r[1] = (bf16)a[1]; r[2] = (bf16)a[2]; r[3] = (bf16)a[3];
    r[4] = (bf16)b[0]; r[5] = (bf16)b[1]; r[6] = (bf16)b[2]; r[7] = (bf16)b[3];
    return r;
}

// LDS tiles: 128-bf16 rows (256 B = 16 chunks), chunk-XOR swizzle (cur/out).
__device__ __forceinline__ int swz128(int row, int col) {
    int c = (col >> 3) ^ (row & 15);
    return row * 256 + c * 16 + (col & 7) * 2;
}
__device__ __forceinline__ int swz256(int row, int col) {
    int c = (col >> 3) ^ (row & 15);
    return row * 512 + c * 16 + (col & 7) * 2;
}

__device__ __forceinline__ void st_pair(char* base, int off, float a, float b) {
    bf16x2 p = {(bf16)a, (bf16)b};
    *(bf16x2*)(base + off) = p;
}

// ---------------------------------------------------------------------------
// prep_kernel: weights -> fragment-linear bf16 (one coalesced 16B load/tile
// in nbr). pw1 tile (kb,ht): lane l holds w1[ht*16+(l&15)][128+kb*32+(l>>4)*8+j].
// pw2 tile (kbh,ot): lane l holds w2[ot*16+(l&15)][kbh*32+(l>>4)*8+j].
// ---------------------------------------------------------------------------
__global__ void prep_kernel(const float* __restrict__ w1,
                            const float* __restrict__ w2,
                            bf16* __restrict__ pw1, bf16* __restrict__ pw2) {
    int s = blockIdx.x * blockDim.x + threadIdx.x;   // 0..2047
    int lane = s & 63, tile = s >> 6;                // tile 0..31
    int li = lane & 15, g = lane >> 4;
    {
        int kb = tile >> 3, ht = tile & 7;
        const float* src = w1 + (size_t)(ht * 16 + li) * 256 + 128 + kb * 32 + g * 8;
        bf16x8 v;
#pragma unroll
        for (int j = 0; j < 8; ++j) v[j] = (bf16)src[j];
        *(bf16x8*)(pw1 + (size_t)s * 8) = v;
    }
    {
        int kbh = tile >> 3, ot = tile & 7;
        const float* src = w2 + (size_t)(ot * 16 + li) * 128 + kbh * 32 + g * 8;
        bf16x8 v;
#pragma unroll
        for (int j = 0; j < 8; ++j) v[j] = (bf16)src[j];
        *(bf16x8*)(pw2 + (size_t)s * 8) = v;
    }
}

// ---------------------------------------------------------------------------
// nbr_kernel: independent waves, one n per wave per loop trip. No barriers.
// ---------------------------------------------------------------------------
__global__ __launch_bounds__(256, 3) void nbr_kernel(
    const float* __restrict__ zn, const float* __restrict__ u1f,
    const bf16* __restrict__ pw1, const bf16* __restrict__ pw2,
    const float* __restrict__ b2, bf16* __restrict__ feat, int N)
{
    __shared__ char lds[4][8192];   // wave-private a1 scratch (L2 A-frag layout)

    const int t = threadIdx.x, w = t >> 6, lane = t & 63;
    const int li = lane & 15, g = lane >> 4;
    char* aflds = lds[w];

    // pre-scaled L2 bias per ot (kernel-lifetime, 8 VGPRs)
    float bc2[8];
#pragma unroll
    for (int ot = 0; ot < 8; ++ot) bc2[ot] = b2[ot * 16 + li] * C2LOG2E;

    const int totWaves = gridDim.x * 4;
    const f32x4 vzero = {0.f, 0.f, 0.f, 0.f};

    for (int n = blockIdx.x * 4 + w; n < N; n += totWaves) {
        // ---- issue u1 loads first (consumed last among inputs) ----
        float uc[8];   // u1 bias (z-half of L1), pre-scaled
#pragma unroll
        for (int ht = 0; ht < 8; ++ht)
            uc[ht] = u1f[(size_t)n * 128 + ht * 16 + li] * C2LOG2E;

        // ---- z_ tile loads (A-frag direct), then convert; zf dies early ----
        f32x4 zf[2][4][2];   // [mt][kb][half]
#pragma unroll
        for (int mt = 0; mt < 2; ++mt)
#pragma unroll
            for (int kb = 0; kb < 4; ++kb) {
                const float* src = zn + ((size_t)n * 32 + 16 * mt + li) * 128 + kb * 32 + g * 8;
                zf[mt][kb][0] = *(const f32x4*)(src);
                zf[mt][kb][1] = *(const f32x4*)(src + 4);
            }
        bf16x8 az[2][4];
#pragma unroll
        for (int mt = 0; mt < 2; ++mt)
#pragma unroll
            for (int kb = 0; kb < 4; ++kb)
                az[mt][kb] = cvt8(zf[mt][kb][0], zf[mt][kb][1]);

        // ---- L1: D1[m][h] over z_-half, weights streamed from pw1 ----
        f32x4 acc1[2][8];
#pragma unroll
        for (int mt = 0; mt < 2; ++mt)
#pragma unroll
            for (int ht = 0; ht < 8; ++ht) acc1[mt][ht] = vzero;

#pragma unroll
        for (int kb = 0; kb < 4; ++kb)
#pragma unroll
            for (int ht = 0; ht < 8; ++ht) {
                bf16x8 wf = *(const bf16x8*)(pw1 + (size_t)((kb * 8 + ht) * 64 + lane) * 8);
                acc1[0][ht] = MFMA(az[0][kb], wf, acc1[0][ht]);
                acc1[1][ht] = MFMA(az[1][kb], wf, acc1[1][ht]);
            }

        // ---- phase B: tanh(acc1 + u1) -> wave-private LDS (L2 A-frag) ----
        // value (mt,ht,r): m = mt*16 + g*4 + r, h = ht*16 + li.
        // consumer frag (mt*4 + ht>>1), lane lc = ((ht&1)*2 + (li>>3))*16 + g*4 + r,
        // j = li&7  ->  byte = (frag*64 + lc)*16 + j*2.
#pragma unroll
        for (int mt = 0; mt < 2; ++mt)
#pragma unroll
            for (int ht = 0; ht < 8; ++ht) {
                int fragbase = ((mt * 4 + (ht >> 1)) * 64 + ((ht & 1) * 2 + (li >> 3)) * 16 + g * 4) * 16
                               + (li & 7) * 2;
#pragma unroll
                for (int r = 0; r < 4; ++r) {
                    float v = fast_tanh_fb(acc1[mt][ht][r], uc[ht]);
                    *(bf16*)(aflds + fragbase + r * 16) = (bf16)v;
                }
            }

        // ---- L2: D2[m][o], a1 from LDS frags, weights from pw2 ----
        f32x4 acc2[2][8];
#pragma unroll
        for (int mt = 0; mt < 2; ++mt)
#pragma unroll
            for (int ot = 0; ot < 8; ++ot) acc2[mt][ot] = vzero;

#pragma unroll
        for (int kbh = 0; kbh < 4; ++kbh) {
            bf16x8 a0 = *(const bf16x8*)(aflds + (size_t)((0 + kbh) * 64 + lane) * 16);
            bf16x8 a1 = *(const bf16x8*)(aflds + (size_t)((4 + kbh) * 64 + lane) * 16);
#pragma unroll
            for (int ot = 0; ot < 8; ++ot) {
                bf16x8 wf = *(const bf16x8*)(pw2 + (size_t)((kbh * 8 + ot) * 64 + lane) * 8);
                acc2[0][ot] = MFMA(a0, wf, acc2[0][ot]);
                acc2[1][ot] = MFMA(a1, wf, acc2[1][ot]);
            }
        }

        // ---- phase D: k-sum of tanh over 32 rows = 32 - 2*sum(rpart) ----
#pragma unroll
        for (int ot = 0; ot < 8; ++ot) {
            float s = 0.f;
#pragma unroll
            for (int mt = 0; mt < 2; ++mt)
#pragma unroll
                for (int r = 0; r < 4; ++r)
                    s += tanh_rpart(acc2[mt][ot][r], bc2[ot]);
            s += __shfl_xor(s, 16);
            s += __shfl_xor(s, 32);
            if (lane < 16) {
                float v = __builtin_fmaf(-2.f, s, 32.f);
                feat[(size_t)n * 256 + 128 + ot * 16 + li] = (bf16)v;
            }
        }
    }
}

// ---------------------------------------------------------------------------
// Kernel A: cur branch (feat[:,0:128]) + u1 = z @ nw1[:,:128]^T + nb1.
// ---------------------------------------------------------------------------
__global__ __launch_bounds__(256, 2) void cur_kernel(
    const float* __restrict__ z,
    const float* __restrict__ w1, const float* __restrict__ b1,
    const float* __restrict__ w2, const float* __restrict__ b2,
    const float* __restrict__ nw1, const float* __restrict__ nb1,
    bf16* __restrict__ feat, float* __restrict__ u1, int N)
{
    __shared__ char z_lds[64 * 256];
    __shared__ char h1_lds[64 * 256];

    const int t = threadIdx.x;
    const int wv = t >> 6, lane = t & 63, g = lane >> 4, li = lane & 15;
    const int hbase = wv * 32;
    const int n0 = blockIdx.x * 64;

    bf16x8 w1f[2][4], w2f[2][4], wzf[2][4];
#pragma unroll
    for (int ht = 0; ht < 2; ++ht)
#pragma unroll
        for (int kb = 0; kb < 4; ++kb) {
            const float* p1 = w1 + (size_t)(hbase + 16*ht + li) * 128 + kb*32 + 8*g;
            w1f[ht][kb] = cvt8(*(const f32x4*)p1, *(const f32x4*)(p1 + 4));
            const float* p2 = w2 + (size_t)(hbase + 16*ht + li) * 128 + kb*32 + 8*g;
            w2f[ht][kb] = cvt8(*(const f32x4*)p2, *(const f32x4*)(p2 + 4));
            const float* p3 = nw1 + (size_t)(hbase + 16*ht + li) * 256 + kb*32 + 8*g;
            wzf[ht][kb] = cvt8(*(const f32x4*)p3, *(const f32x4*)(p3 + 4));
        }
    float b1v[2][4], b2v[2][4], bnv[2][4];
#pragma unroll
    for (int ht = 0; ht < 2; ++ht)
#pragma unroll
        for (int rr = 0; rr < 4; ++rr) {
            b1v[ht][rr] = b1[hbase + 16*ht + 4*g + rr];
            b2v[ht][rr] = b2[hbase + 16*ht + 4*g + rr];
            bnv[ht][rr] = nb1[hbase + 16*ht + 4*g + rr];
        }

    {
        int m = t >> 2;
        int c0 = (t & 3) * 32;
        int row = n0 + m; if (row > N - 1) row = N - 1;
        const float* src = z + (size_t)row * 128 + c0;
#pragma unroll
        for (int q = 0; q < 4; ++q) {
            f32x4 a = *(const f32x4*)(src + 8*q);
            f32x4 b = *(const f32x4*)(src + 8*q + 4);
            *(bf16x8*)(z_lds + swz128(m, c0 + 8*q)) = cvt8(a, b);
        }
    }
    __syncthreads();

    const f32x4 vzero = {0.f, 0.f, 0.f, 0.f};
    f32x4 acc1[2][4], accz[2][4];
#pragma unroll
    for (int a = 0; a < 2; ++a)
#pragma unroll
        for (int b = 0; b < 4; ++b) { acc1[a][b] = vzero; accz[a][b] = vzero; }

#pragma unroll
    for (int kb = 0; kb < 4; ++kb) {
        bf16x8 bz[4];
#pragma unroll
        for (int mt = 0; mt < 4; ++mt)
            bz[mt] = *(const bf16x8*)(z_lds + swz128(16*mt + li, kb*32 + 8*g));
#pragma unroll
        for (int ht = 0; ht < 2; ++ht)
#pragma unroll
            for (int mt = 0; mt < 4; ++mt) {
                acc1[ht][mt] = MFMA(w1f[ht][kb], bz[mt], acc1[ht][mt]);
                accz[ht][mt] = MFMA(wzf[ht][kb], bz[mt], accz[ht][mt]);
            }
    }

#pragma unroll
    for (int ht = 0; ht < 2; ++ht)
#pragma unroll
        for (int mt = 0; mt < 4; ++mt) {
            int row = n0 + 16*mt + li;
            if (row < N) {
                f32x4 v;
#pragma unroll
                for (int rr = 0; rr < 4; ++rr) v[rr] = accz[ht][mt][rr] + bnv[ht][rr];
                *(f32x4*)(u1 + (size_t)row * 128 + hbase + 16*ht + 4*g) = v;
            }
        }

#pragma unroll
    for (int ht = 0; ht < 2; ++ht)
#pragma unroll
        for (int mt = 0; mt < 4; ++mt) {
            float v0 = fast_tanh(acc1[ht][mt][0] + b1v[ht][0]);
            float v1 = fast_tanh(acc1[ht][mt][1] + b1v[ht][1]);
            float v2 = fast_tanh(acc1[ht][mt][2] + b1v[ht][2]);
            float v3 = fast_tanh(acc1[ht][mt][3] + b1v[ht][3]);
            int m = 16*mt + li;
            int h = hbase + 16*ht + 4*g;
            st_pair(h1_lds, swz128(m, h),     v0, v1);
            st_pair(h1_lds, swz128(m, h + 2), v2, v3);
        }
    __syncthreads();

    f32x4 acc2[2][4];
#pragma unroll
    for (int a = 0; a < 2; ++a)
#pragma unroll
        for (int b = 0; b < 4; ++b) acc2[a][b] = vzero;

#pragma unroll
    for (int kb = 0; kb < 4; ++kb) {
        bf16x8 bh[4];
#pragma unroll
        for (int mt = 0; mt < 4; ++mt)
            bh[mt] = *(const bf16x8*)(h1_lds + swz128(16*mt + li, kb*32 + 8*g));
#pragma unroll
        for (int ht = 0; ht < 2; ++ht)
#pragma unroll
            for (int mt = 0; mt < 4; ++mt)
                acc2[ht][mt] = MFMA(w2f[ht][kb], bh[mt], acc2[ht][mt]);
    }
#pragma unroll
    for (int ht = 0; ht < 2; ++ht)
#pragma unroll
        for (int mt = 0; mt < 4; ++mt) {
            float v0 = fast_tanh(acc2[ht][mt][0] + b2v[ht][0]);
            float v1 = fast_tanh(acc2[ht][mt][1] + b2v[ht][1]);
            float v2 = fast_tanh(acc2[ht][mt][2] + b2v[ht][2]);
            float v3 = fast_tanh(acc2[ht][mt][3] + b2v[ht][3]);
            int row = n0 + 16*mt + li;
            if (row < N) {
                int h = hbase + 16*ht + 4*g;
                bf16* dst = feat + (size_t)row * 256 + h;
                bf16x2 p01 = {(bf16)v0, (bf16)v1};
                bf16x2 p23 = {(bf16)v2, (bf16)v3};
                *(bf16x2*)(dst)     = p01;
                *(bf16x2*)(dst + 2) = p23;
            }
        }
}

// ---------------------------------------------------------------------------
// Kernel C: dc = feat[N,256] @ ow^T + ob -> f32 out. 64 rows/block.
// ---------------------------------------------------------------------------
__global__ __launch_bounds__(256, 2) void out_kernel(
    const bf16* __restrict__ feat,
    const float* __restrict__ ow, const float* __restrict__ ob,
    float* __restrict__ out, int N)
{
    __shared__ char f_lds[64 * 512];

    const int t = threadIdx.x, wv = t >> 6, lane = t & 63, g = lane >> 4, li = lane & 15;
    const int cbase = wv * 16;
    const int n0 = blockIdx.x * 64;

    bf16x8 owf[8];
#pragma unroll
    for (int kb = 0; kb < 8; ++kb) {
        const float* p = ow + (size_t)(cbase + li) * 256 + kb*32 + 8*g;
        owf[kb] = cvt8(*(const f32x4*)p, *(const f32x4*)(p + 4));
    }
    float obv = ob[cbase + li];

    {
        int m = t >> 2;
        int c0 = (t & 3) * 64;
        int row = n0 + m; if (row > N - 1) row = N - 1;
        const bf16* src = feat + (size_t)row * 256 + c0;
#pragma unroll
        for (int q = 0; q < 8; ++q)
            *(bf16x8*)(f_lds + swz256(m, c0 + 8*q)) = *(const bf16x8*)(src + 8*q);
    }
    __syncthreads();

    const f32x4 vzero = {0.f, 0.f, 0.f, 0.f};
    f32x4 acc[4];
#pragma unroll
    for (int a = 0; a < 4; ++a) acc[a] = vzero;

#pragma unroll
    for (int kb = 0; kb < 8; ++kb) {
        bf16x8 af[4];
#pragma unroll
        for (int mt = 0; mt < 4; ++mt)
            af[mt] = *(const bf16x8*)(f_lds + swz256(16*mt + li, kb*32 + 8*g));
#pragma unroll
        for (int mt = 0; mt < 4; ++mt)
            acc[mt] = MFMA(af[mt], owf[kb], acc[mt]);
    }
#pragma unroll
    for (int mt = 0; mt < 4; ++mt)
#pragma unroll
        for (int rr = 0; rr < 4; ++rr) {
            int row = n0 + 16*mt + 4*g + rr;
            if (row < N) out[(size_t)row * 64 + cbase + li] = acc[mt][rr] + obv;
        }
}

// ---------------------------------------------------------------------------
extern "C" void kernel_launch(void* const* d_in, const int* in_sizes, int n_in,
                              void* d_out, int out_size, void* d_ws, size_t ws_size,
                              hipStream_t stream) {
    const float* z   = (const float*)d_in[0];
    const float* zn  = (const float*)d_in[1];
    const float* cw1 = (const float*)d_in[2];
    const float* cb1 = (const float*)d_in[3];
    const float* cw2 = (const float*)d_in[4];
    const float* cb2 = (const float*)d_in[5];
    const float* nw1 = (const float*)d_in[6];
    const float* nb1 = (const float*)d_in[7];
    const float* nw2 = (const float*)d_in[8];
    const float* nb2 = (const float*)d_in[9];
    const float* ow  = (const float*)d_in[10];
    const float* ob  = (const float*)d_in[11];
    float* out = (float*)d_out;

    const int N = in_sizes[0] / 128;           // 20000
    const int nblk = (N + 63) / 64;            // 313

    char* ws = (char*)d_ws;
    bf16*  feat = (bf16*)ws;                                   // [N][256] bf16
    float* u1   = (float*)(ws + (size_t)N * 256 * sizeof(bf16)); // [N][128] f32
    bf16*  pw1  = (bf16*)(ws + (size_t)N * 256 * sizeof(bf16) + (size_t)N * 128 * sizeof(float));
    bf16*  pw2  = pw1 + 2048 * 8;              // 32 KB each

    (void)n_in; (void)out_size; (void)ws_size;

    prep_kernel<<<8, 256, 0, stream>>>(nw1, nw2, pw1, pw2);
    cur_kernel<<<nblk, 256, 0, stream>>>(z, cw1, cb1, cw2, cb2, nw1, nb1, feat, u1, N);
    nbr_kernel<<<768, 256, 0, stream>>>(zn, u1, pw1, pw2, nb2, feat, N);
    out_kernel<<<nblk, 256, 0, stream>>>(feat, ow, ob, out, N);
}

// Round 7
// 259.291 us; speedup vs baseline: 1.6337x; 1.3715x over previous
//
#include <hip/hip_runtime.h>

// ---------------------------------------------------------------------------
// MLP-GNN fused op for MI355X (gfx950).
//   v  = tanh(tanh(z @ cw1^T + cb1) @ cw2^T + cb2)                    [N,128]
//   vn = tanh(tanh([z|z_] @ nw1^T + nb1) @ nw2^T + nb2).sum(axis=K)   [N,128]
//   dc = [v | vn] @ ow^T + ob                                         [N,64]
// nbr_kernel: fully independent waves (zero barriers), one n per wave trip:
//   z_ tile -> MFMA A-frags direct from global; weights streamed from
//   frag-linear bf16 arrays (prep_kernel, L2-resident); L1 tanh -> wave-
//   private LDS scratch (in-order DS, no barrier) -> L2 -> k-sum -> feat.
// R7 spill fix: R5/R6 both clamped to VGPR_Count=84 = arch half of the
// 3-waves/EU budget on gfx950's UNIFIED VGPR/AGPR file (168 = 84+84) ->
// zf spilled (176-300 MB scratch writes). launch_bounds(256,2) gives the
// 2-waves/EU budget (256 = 128 arch + 128 acc); arch live ~110 fits.
// Grid = 512 = exactly 2 blocks/CU co-resident.
// ---------------------------------------------------------------------------

typedef __bf16 bf16;
typedef __bf16 bf16x2 __attribute__((ext_vector_type(2)));
typedef __bf16 bf16x8 __attribute__((ext_vector_type(8)));
typedef float  f32x4  __attribute__((ext_vector_type(4)));

#define MFMA(a, b, c) __builtin_amdgcn_mfma_f32_16x16x32_bf16((a), (b), (c), 0, 0, 0)

#define C2LOG2E 2.885390081777927f   // 2*log2(e)

// tanh(x) = 1 - 2/(exp2(2*log2e*x)+1) — all signs, inf-safe.
__device__ __forceinline__ float fast_tanh(float x) {
    float t = __builtin_amdgcn_exp2f(x * C2LOG2E);
    return 1.0f - 2.0f * __builtin_amdgcn_rcpf(t + 1.0f);
}
// tanh(acc + u) with pre-scaled bias uc = u*C2LOG2E.
__device__ __forceinline__ float fast_tanh_fb(float acc, float uc) {
    float t = __builtin_amdgcn_exp2f(__builtin_fmaf(acc, C2LOG2E, uc));
    return 1.0f - 2.0f * __builtin_amdgcn_rcpf(t + 1.0f);
}
// r-part only: rcp(exp2(fma)+1); caller uses sum = count - 2*sum(r).
__device__ __forceinline__ float tanh_rpart(float acc, float uc) {
    float t = __builtin_amdgcn_exp2f(__builtin_fmaf(acc, C2LOG2E, uc));
    return __builtin_amdgcn_rcpf(t + 1.0f);
}

__device__ __forceinline__ bf16x8 cvt8(f32x4 a, f32x4 b) {
    bf16x8 r;
    r[0] = (bf16)a[0]; r[1] = (bf16)a[1]; r[2] = (bf16)a[2]; r[3] = (bf16)a[3];
    r[4] = (bf16)b[0]; r[5] = (bf16)b[1]; r[6] = (bf16)b[2]; r[7] = (bf16)b[3];
    return r;
}

// LDS tiles: 128-bf16 rows (256 B = 16 chunks), chunk-XOR swizzle (cur/out).
__device__ __forceinline__ int swz128(int row, int col) {
    int c = (col >> 3) ^ (row & 15);
    return row * 256 + c * 16 + (col & 7) * 2;
}
__device__ __forceinline__ int swz256(int row, int col) {
    int c = (col >> 3) ^ (row & 15);
    return row * 512 + c * 16 + (col & 7) * 2;
}

__device__ __forceinline__ void st_pair(char* base, int off, float a, float b) {
    bf16x2 p = {(bf16)a, (bf16)b};
    *(bf16x2*)(base + off) = p;
}

// ---------------------------------------------------------------------------
// prep_kernel: weights -> fragment-linear bf16 (one coalesced 16B load/tile
// in nbr). pw1 tile (kb,ht): lane l holds w1[ht*16+(l&15)][128+kb*32+(l>>4)*8+j].
// pw2 tile (kbh,ot): lane l holds w2[ot*16+(l&15)][kbh*32+(l>>4)*8+j].
// ---------------------------------------------------------------------------
__global__ void prep_kernel(const float* __restrict__ w1,
                            const float* __restrict__ w2,
                            bf16* __restrict__ pw1, bf16* __restrict__ pw2) {
    int s = blockIdx.x * blockDim.x + threadIdx.x;   // 0..2047
    int lane = s & 63, tile = s >> 6;                // tile 0..31
    int li = lane & 15, g = lane >> 4;
    {
        int kb = tile >> 3, ht = tile & 7;
        const float* src = w1 + (size_t)(ht * 16 + li) * 256 + 128 + kb * 32 + g * 8;
        bf16x8 v;
#pragma unroll
        for (int j = 0; j < 8; ++j) v[j] = (bf16)src[j];
        *(bf16x8*)(pw1 + (size_t)s * 8) = v;
    }
    {
        int kbh = tile >> 3, ot = tile & 7;
        const float* src = w2 + (size_t)(ot * 16 + li) * 128 + kbh * 32 + g * 8;
        bf16x8 v;
#pragma unroll
        for (int j = 0; j < 8; ++j) v[j] = (bf16)src[j];
        *(bf16x8*)(pw2 + (size_t)s * 8) = v;
    }
}

// ---------------------------------------------------------------------------
// nbr_kernel: independent waves, one n per wave per loop trip. No barriers.
// ---------------------------------------------------------------------------
__global__ __launch_bounds__(256, 2) void nbr_kernel(
    const float* __restrict__ zn, const float* __restrict__ u1f,
    const bf16* __restrict__ pw1, const bf16* __restrict__ pw2,
    const float* __restrict__ b2, bf16* __restrict__ feat, int N)
{
    __shared__ char lds[4][8192];   // wave-private a1 scratch (L2 A-frag layout)

    const int t = threadIdx.x, w = t >> 6, lane = t & 63;
    const int li = lane & 15, g = lane >> 4;
    char* aflds = lds[w];

    // pre-scaled L2 bias per ot (kernel-lifetime, 8 VGPRs)
    float bc2[8];
#pragma unroll
    for (int ot = 0; ot < 8; ++ot) bc2[ot] = b2[ot * 16 + li] * C2LOG2E;

    const int totWaves = gridDim.x * 4;
    const f32x4 vzero = {0.f, 0.f, 0.f, 0.f};

    for (int n = blockIdx.x * 4 + w; n < N; n += totWaves) {
        // ---- issue u1 loads first (consumed last among inputs) ----
        float uc[8];   // u1 bias (z-half of L1), pre-scaled
#pragma unroll
        for (int ht = 0; ht < 8; ++ht)
            uc[ht] = u1f[(size_t)n * 128 + ht * 16 + li] * C2LOG2E;

        // ---- z_ tile loads (A-frag direct), then convert; zf dies early ----
        f32x4 zf[2][4][2];   // [mt][kb][half]
#pragma unroll
        for (int mt = 0; mt < 2; ++mt)
#pragma unroll
            for (int kb = 0; kb < 4; ++kb) {
                const float* src = zn + ((size_t)n * 32 + 16 * mt + li) * 128 + kb * 32 + g * 8;
                zf[mt][kb][0] = *(const f32x4*)(src);
                zf[mt][kb][1] = *(const f32x4*)(src + 4);
            }
        bf16x8 az[2][4];
#pragma unroll
        for (int mt = 0; mt < 2; ++mt)
#pragma unroll
            for (int kb = 0; kb < 4; ++kb)
                az[mt][kb] = cvt8(zf[mt][kb][0], zf[mt][kb][1]);

        // ---- L1: D1[m][h] over z_-half, weights streamed from pw1 ----
        f32x4 acc1[2][8];
#pragma unroll
        for (int mt = 0; mt < 2; ++mt)
#pragma unroll
            for (int ht = 0; ht < 8; ++ht) acc1[mt][ht] = vzero;

#pragma unroll
        for (int kb = 0; kb < 4; ++kb)
#pragma unroll
            for (int ht = 0; ht < 8; ++ht) {
                bf16x8 wf = *(const bf16x8*)(pw1 + (size_t)((kb * 8 + ht) * 64 + lane) * 8);
                acc1[0][ht] = MFMA(az[0][kb], wf, acc1[0][ht]);
                acc1[1][ht] = MFMA(az[1][kb], wf, acc1[1][ht]);
            }

        // ---- phase B: tanh(acc1 + u1) -> wave-private LDS (L2 A-frag) ----
        // value (mt,ht,r): m = mt*16 + g*4 + r, h = ht*16 + li.
        // consumer frag (mt*4 + ht>>1), lane lc = ((ht&1)*2 + (li>>3))*16 + g*4 + r,
        // j = li&7  ->  byte = (frag*64 + lc)*16 + j*2.
#pragma unroll
        for (int mt = 0; mt < 2; ++mt)
#pragma unroll
            for (int ht = 0; ht < 8; ++ht) {
                int fragbase = ((mt * 4 + (ht >> 1)) * 64 + ((ht & 1) * 2 + (li >> 3)) * 16 + g * 4) * 16
                               + (li & 7) * 2;
#pragma unroll
                for (int r = 0; r < 4; ++r) {
                    float v = fast_tanh_fb(acc1[mt][ht][r], uc[ht]);
                    *(bf16*)(aflds + fragbase + r * 16) = (bf16)v;
                }
            }

        // ---- L2: D2[m][o], a1 from LDS frags, weights from pw2 ----
        f32x4 acc2[2][8];
#pragma unroll
        for (int mt = 0; mt < 2; ++mt)
#pragma unroll
            for (int ot = 0; ot < 8; ++ot) acc2[mt][ot] = vzero;

#pragma unroll
        for (int kbh = 0; kbh < 4; ++kbh) {
            bf16x8 a0 = *(const bf16x8*)(aflds + (size_t)((0 + kbh) * 64 + lane) * 16);
            bf16x8 a1 = *(const bf16x8*)(aflds + (size_t)((4 + kbh) * 64 + lane) * 16);
#pragma unroll
            for (int ot = 0; ot < 8; ++ot) {
                bf16x8 wf = *(const bf16x8*)(pw2 + (size_t)((kbh * 8 + ot) * 64 + lane) * 8);
                acc2[0][ot] = MFMA(a0, wf, acc2[0][ot]);
                acc2[1][ot] = MFMA(a1, wf, acc2[1][ot]);
            }
        }

        // ---- phase D: k-sum of tanh over 32 rows = 32 - 2*sum(rpart) ----
#pragma unroll
        for (int ot = 0; ot < 8; ++ot) {
            float s = 0.f;
#pragma unroll
            for (int mt = 0; mt < 2; ++mt)
#pragma unroll
                for (int r = 0; r < 4; ++r)
                    s += tanh_rpart(acc2[mt][ot][r], bc2[ot]);
            s += __shfl_xor(s, 16);
            s += __shfl_xor(s, 32);
            if (lane < 16) {
                float v = __builtin_fmaf(-2.f, s, 32.f);
                feat[(size_t)n * 256 + 128 + ot * 16 + li] = (bf16)v;
            }
        }
    }
}

// ---------------------------------------------------------------------------
// Kernel A: cur branch (feat[:,0:128]) + u1 = z @ nw1[:,:128]^T + nb1.
// ---------------------------------------------------------------------------
__global__ __launch_bounds__(256, 2) void cur_kernel(
    const float* __restrict__ z,
    const float* __restrict__ w1, const float* __restrict__ b1,
    const float* __restrict__ w2, const float* __restrict__ b2,
    const float* __restrict__ nw1, const float* __restrict__ nb1,
    bf16* __restrict__ feat, float* __restrict__ u1, int N)
{
    __shared__ char z_lds[64 * 256];
    __shared__ char h1_lds[64 * 256];

    const int t = threadIdx.x;
    const int wv = t >> 6, lane = t & 63, g = lane >> 4, li = lane & 15;
    const int hbase = wv * 32;
    const int n0 = blockIdx.x * 64;

    bf16x8 w1f[2][4], w2f[2][4], wzf[2][4];
#pragma unroll
    for (int ht = 0; ht < 2; ++ht)
#pragma unroll
        for (int kb = 0; kb < 4; ++kb) {
            const float* p1 = w1 + (size_t)(hbase + 16*ht + li) * 128 + kb*32 + 8*g;
            w1f[ht][kb] = cvt8(*(const f32x4*)p1, *(const f32x4*)(p1 + 4));
            const float* p2 = w2 + (size_t)(hbase + 16*ht + li) * 128 + kb*32 + 8*g;
            w2f[ht][kb] = cvt8(*(const f32x4*)p2, *(const f32x4*)(p2 + 4));
            const float* p3 = nw1 + (size_t)(hbase + 16*ht + li) * 256 + kb*32 + 8*g;
            wzf[ht][kb] = cvt8(*(const f32x4*)p3, *(const f32x4*)(p3 + 4));
        }
    float b1v[2][4], b2v[2][4], bnv[2][4];
#pragma unroll
    for (int ht = 0; ht < 2; ++ht)
#pragma unroll
        for (int rr = 0; rr < 4; ++rr) {
            b1v[ht][rr] = b1[hbase + 16*ht + 4*g + rr];
            b2v[ht][rr] = b2[hbase + 16*ht + 4*g + rr];
            bnv[ht][rr] = nb1[hbase + 16*ht + 4*g + rr];
        }

    {
        int m = t >> 2;
        int c0 = (t & 3) * 32;
        int row = n0 + m; if (row > N - 1) row = N - 1;
        const float* src = z + (size_t)row * 128 + c0;
#pragma unroll
        for (int q = 0; q < 4; ++q) {
            f32x4 a = *(const f32x4*)(src + 8*q);
            f32x4 b = *(const f32x4*)(src + 8*q + 4);
            *(bf16x8*)(z_lds + swz128(m, c0 + 8*q)) = cvt8(a, b);
        }
    }
    __syncthreads();

    const f32x4 vzero = {0.f, 0.f, 0.f, 0.f};
    f32x4 acc1[2][4], accz[2][4];
#pragma unroll
    for (int a = 0; a < 2; ++a)
#pragma unroll
        for (int b = 0; b < 4; ++b) { acc1[a][b] = vzero; accz[a][b] = vzero; }

#pragma unroll
    for (int kb = 0; kb < 4; ++kb) {
        bf16x8 bz[4];
#pragma unroll
        for (int mt = 0; mt < 4; ++mt)
            bz[mt] = *(const bf16x8*)(z_lds + swz128(16*mt + li, kb*32 + 8*g));
#pragma unroll
        for (int ht = 0; ht < 2; ++ht)
#pragma unroll
            for (int mt = 0; mt < 4; ++mt) {
                acc1[ht][mt] = MFMA(w1f[ht][kb], bz[mt], acc1[ht][mt]);
                accz[ht][mt] = MFMA(wzf[ht][kb], bz[mt], accz[ht][mt]);
            }
    }

#pragma unroll
    for (int ht = 0; ht < 2; ++ht)
#pragma unroll
        for (int mt = 0; mt < 4; ++mt) {
            int row = n0 + 16*mt + li;
            if (row < N) {
                f32x4 v;
#pragma unroll
                for (int rr = 0; rr < 4; ++rr) v[rr] = accz[ht][mt][rr] + bnv[ht][rr];
                *(f32x4*)(u1 + (size_t)row * 128 + hbase + 16*ht + 4*g) = v;
            }
        }

#pragma unroll
    for (int ht = 0; ht < 2; ++ht)
#pragma unroll
        for (int mt = 0; mt < 4; ++mt) {
            float v0 = fast_tanh(acc1[ht][mt][0] + b1v[ht][0]);
            float v1 = fast_tanh(acc1[ht][mt][1] + b1v[ht][1]);
            float v2 = fast_tanh(acc1[ht][mt][2] + b1v[ht][2]);
            float v3 = fast_tanh(acc1[ht][mt][3] + b1v[ht][3]);
            int m = 16*mt + li;
            int h = hbase + 16*ht + 4*g;
            st_pair(h1_lds, swz128(m, h),     v0, v1);
            st_pair(h1_lds, swz128(m, h + 2), v2, v3);
        }
    __syncthreads();

    f32x4 acc2[2][4];
#pragma unroll
    for (int a = 0; a < 2; ++a)
#pragma unroll
        for (int b = 0; b < 4; ++b) acc2[a][b] = vzero;

#pragma unroll
    for (int kb = 0; kb < 4; ++kb) {
        bf16x8 bh[4];
#pragma unroll
        for (int mt = 0; mt < 4; ++mt)
            bh[mt] = *(const bf16x8*)(h1_lds + swz128(16*mt + li, kb*32 + 8*g));
#pragma unroll
        for (int ht = 0; ht < 2; ++ht)
#pragma unroll
            for (int mt = 0; mt < 4; ++mt)
                acc2[ht][mt] = MFMA(w2f[ht][kb], bh[mt], acc2[ht][mt]);
    }
#pragma unroll
    for (int ht = 0; ht < 2; ++ht)
#pragma unroll
        for (int mt = 0; mt < 4; ++mt) {
            float v0 = fast_tanh(acc2[ht][mt][0] + b2v[ht][0]);
            float v1 = fast_tanh(acc2[ht][mt][1] + b2v[ht][1]);
            float v2 = fast_tanh(acc2[ht][mt][2] + b2v[ht][2]);
            float v3 = fast_tanh(acc2[ht][mt][3] + b2v[ht][3]);
            int row = n0 + 16*mt + li;
            if (row < N) {
                int h = hbase + 16*ht + 4*g;
                bf16* dst = feat + (size_t)row * 256 + h;
                bf16x2 p01 = {(bf16)v0, (bf16)v1};
                bf16x2 p23 = {(bf16)v2, (bf16)v3};
                *(bf16x2*)(dst)     = p01;
                *(bf16x2*)(dst + 2) = p23;
            }
        }
}

// ---------------------------------------------------------------------------
// Kernel C: dc = feat[N,256] @ ow^T + ob -> f32 out. 64 rows/block.
// ---------------------------------------------------------------------------
__global__ __launch_bounds__(256, 2) void out_kernel(
    const bf16* __restrict__ feat,
    const float* __restrict__ ow, const float* __restrict__ ob,
    float* __restrict__ out, int N)
{
    __shared__ char f_lds[64 * 512];

    const int t = threadIdx.x, wv = t >> 6, lane = t & 63, g = lane >> 4, li = lane & 15;
    const int cbase = wv * 16;
    const int n0 = blockIdx.x * 64;

    bf16x8 owf[8];
#pragma unroll
    for (int kb = 0; kb < 8; ++kb) {
        const float* p = ow + (size_t)(cbase + li) * 256 + kb*32 + 8*g;
        owf[kb] = cvt8(*(const f32x4*)p, *(const f32x4*)(p + 4));
    }
    float obv = ob[cbase + li];

    {
        int m = t >> 2;
        int c0 = (t & 3) * 64;
        int row = n0 + m; if (row > N - 1) row = N - 1;
        const bf16* src = feat + (size_t)row * 256 + c0;
#pragma unroll
        for (int q = 0; q < 8; ++q)
            *(bf16x8*)(f_lds + swz256(m, c0 + 8*q)) = *(const bf16x8*)(src + 8*q);
    }
    __syncthreads();

    const f32x4 vzero = {0.f, 0.f, 0.f, 0.f};
    f32x4 acc[4];
#pragma unroll
    for (int a = 0; a < 4; ++a) acc[a] = vzero;

#pragma unroll
    for (int kb = 0; kb < 8; ++kb) {
        bf16x8 af[4];
#pragma unroll
        for (int mt = 0; mt < 4; ++mt)
            af[mt] = *(const bf16x8*)(f_lds + swz256(16*mt + li, kb*32 + 8*g));
#pragma unroll
        for (int mt = 0; mt < 4; ++mt)
            acc[mt] = MFMA(af[mt], owf[kb], acc[mt]);
    }
#pragma unroll
    for (int mt = 0; mt < 4; ++mt)
#pragma unroll
        for (int rr = 0; rr < 4; ++rr) {
            int row = n0 + 16*mt + 4*g + rr;
            if (row < N) out[(size_t)row * 64 + cbase + li] = acc[mt][rr] + obv;
        }
}

// ---------------------------------------------------------------------------
extern "C" void kernel_launch(void* const* d_in, const int* in_sizes, int n_in,
                              void* d_out, int out_size, void* d_ws, size_t ws_size,
                              hipStream_t stream) {
    const float* z   = (const float*)d_in[0];
    const float* zn  = (const float*)d_in[1];
    const float* cw1 = (const float*)d_in[2];
    const float* cb1 = (const float*)d_in[3];
    const float* cw2 = (const float*)d_in[4];
    const float* cb2 = (const float*)d_in[5];
    const float* nw1 = (const float*)d_in[6];
    const float* nb1 = (const float*)d_in[7];
    const float* nw2 = (const float*)d_in[8];
    const float* nb2 = (const float*)d_in[9];
    const float* ow  = (const float*)d_in[10];
    const float* ob  = (const float*)d_in[11];
    float* out = (float*)d_out;

    const int N = in_sizes[0] / 128;           // 20000
    const int nblk = (N + 63) / 64;            // 313

    char* ws = (char*)d_ws;
    bf16*  feat = (bf16*)ws;                                   // [N][256] bf16
    float* u1   = (float*)(ws + (size_t)N * 256 * sizeof(bf16)); // [N][128] f32
    bf16*  pw1  = (bf16*)(ws + (size_t)N * 256 * sizeof(bf16) + (size_t)N * 128 * sizeof(float));
    bf16*  pw2  = pw1 + 2048 * 8;              // 32 KB each

    (void)n_in; (void)out_size; (void)ws_size;

    prep_kernel<<<8, 256, 0, stream>>>(nw1, nw2, pw1, pw2);
    cur_kernel<<<nblk, 256, 0, stream>>>(z, cw1, cb1, cw2, cb2, nw1, nb1, feat, u1, N);
    nbr_kernel<<<512, 256, 0, stream>>>(zn, u1, pw1, pw2, nb2, feat, N);
    out_kernel<<<nblk, 256, 0, stream>>>(feat, ow, ob, out, N);
}

// Round 8
// 246.041 us; speedup vs baseline: 1.7217x; 1.0539x over previous
//
#include <hip/hip_runtime.h>

// ---------------------------------------------------------------------------
// MLP-GNN fused op for MI355X (gfx950).
//   v  = tanh(tanh(z @ cw1^T + cb1) @ cw2^T + cb2)                    [N,128]
//   vn = tanh(tanh([z|z_] @ nw1^T + nb1) @ nw2^T + nb2).sum(axis=K)   [N,128]
//   dc = [v | vn] @ ow^T + ob                                         [N,64]
// nbr_kernel: fully independent waves (zero barriers), one n per wave trip.
// R8 spill fix: R7 still allocated the full 128-arch cap and spilled (WRITE
// 76 MB, FETCH +170 MB): all 16 zf staging loads were batched (64 regs live).
// Split staging into two mt-halves with a sched_barrier(0) between, so peak
// arch live ~95 < 128. TLP (8 indep waves/CU) covers the extra wait.
// ---------------------------------------------------------------------------

typedef __bf16 bf16;
typedef __bf16 bf16x2 __attribute__((ext_vector_type(2)));
typedef __bf16 bf16x8 __attribute__((ext_vector_type(8)));
typedef float  f32x4  __attribute__((ext_vector_type(4)));

#define MFMA(a, b, c) __builtin_amdgcn_mfma_f32_16x16x32_bf16((a), (b), (c), 0, 0, 0)

#define C2LOG2E 2.885390081777927f   // 2*log2(e)

// tanh(x) = 1 - 2/(exp2(2*log2e*x)+1) — all signs, inf-safe.
__device__ __forceinline__ float fast_tanh(float x) {
    float t = __builtin_amdgcn_exp2f(x * C2LOG2E);
    return 1.0f - 2.0f * __builtin_amdgcn_rcpf(t + 1.0f);
}
// tanh(acc + u) with pre-scaled bias uc = u*C2LOG2E.
__device__ __forceinline__ float fast_tanh_fb(float acc, float uc) {
    float t = __builtin_amdgcn_exp2f(__builtin_fmaf(acc, C2LOG2E, uc));
    return 1.0f - 2.0f * __builtin_amdgcn_rcpf(t + 1.0f);
}
// r-part only: rcp(exp2(fma)+1); caller uses sum = count - 2*sum(r).
__device__ __forceinline__ float tanh_rpart(float acc, float uc) {
    float t = __builtin_amdgcn_exp2f(__builtin_fmaf(acc, C2LOG2E, uc));
    return __builtin_amdgcn_rcpf(t + 1.0f);
}

__device__ __forceinline__ bf16x8 cvt8(f32x4 a, f32x4 b) {
    bf16x8 r;
    r[0] = (bf16)a[0]; r[1] = (bf16)a[1]; r[2] = (bf16)a[2]; r[3] = (bf16)a[3];
    r[4] = (bf16)b[0]; r[5] = (bf16)b[1]; r[6] = (bf16)b[2]; r[7] = (bf16)b[3];
    return r;
}

// LDS tiles: 128-bf16 rows (256 B = 16 chunks), chunk-XOR swizzle (cur/out).
__device__ __forceinline__ int swz128(int row, int col) {
    int c = (col >> 3) ^ (row & 15);
    return row * 256 + c * 16 + (col & 7) * 2;
}
__device__ __forceinline__ int swz256(int row, int col) {
    int c = (col >> 3) ^ (row & 15);
    return row * 512 + c * 16 + (col & 7) * 2;
}

__device__ __forceinline__ void st_pair(char* base, int off, float a, float b) {
    bf16x2 p = {(bf16)a, (bf16)b};
    *(bf16x2*)(base + off) = p;
}

// ---------------------------------------------------------------------------
// prep_kernel: weights -> fragment-linear bf16 (one coalesced 16B load/tile
// in nbr). pw1 tile (kb,ht): lane l holds w1[ht*16+(l&15)][128+kb*32+(l>>4)*8+j].
// pw2 tile (kbh,ot): lane l holds w2[ot*16+(l&15)][kbh*32+(l>>4)*8+j].
// ---------------------------------------------------------------------------
__global__ void prep_kernel(const float* __restrict__ w1,
                            const float* __restrict__ w2,
                            bf16* __restrict__ pw1, bf16* __restrict__ pw2) {
    int s = blockIdx.x * blockDim.x + threadIdx.x;   // 0..2047
    int lane = s & 63, tile = s >> 6;                // tile 0..31
    int li = lane & 15, g = lane >> 4;
    {
        int kb = tile >> 3, ht = tile & 7;
        const float* src = w1 + (size_t)(ht * 16 + li) * 256 + 128 + kb * 32 + g * 8;
        bf16x8 v;
#pragma unroll
        for (int j = 0; j < 8; ++j) v[j] = (bf16)src[j];
        *(bf16x8*)(pw1 + (size_t)s * 8) = v;
    }
    {
        int kbh = tile >> 3, ot = tile & 7;
        const float* src = w2 + (size_t)(ot * 16 + li) * 128 + kbh * 32 + g * 8;
        bf16x8 v;
#pragma unroll
        for (int j = 0; j < 8; ++j) v[j] = (bf16)src[j];
        *(bf16x8*)(pw2 + (size_t)s * 8) = v;
    }
}

// ---------------------------------------------------------------------------
// nbr_kernel: independent waves, one n per wave per loop trip. No barriers.
// ---------------------------------------------------------------------------
__global__ __launch_bounds__(256, 2) void nbr_kernel(
    const float* __restrict__ zn, const float* __restrict__ u1f,
    const bf16* __restrict__ pw1, const bf16* __restrict__ pw2,
    const float* __restrict__ b2, bf16* __restrict__ feat, int N)
{
    __shared__ char lds[4][8192];   // wave-private a1 scratch (L2 A-frag layout)

    const int t = threadIdx.x, w = t >> 6, lane = t & 63;
    const int li = lane & 15, g = lane >> 4;
    char* aflds = lds[w];

    // pre-scaled L2 bias per ot (kernel-lifetime, 8 VGPRs)
    float bc2[8];
#pragma unroll
    for (int ot = 0; ot < 8; ++ot) bc2[ot] = b2[ot * 16 + li] * C2LOG2E;

    const int totWaves = gridDim.x * 4;
    const f32x4 vzero = {0.f, 0.f, 0.f, 0.f};

    for (int n = blockIdx.x * 4 + w; n < N; n += totWaves) {
        // ---- issue u1 loads first (consumed last among inputs) ----
        float uc[8];   // u1 bias (z-half of L1), pre-scaled
#pragma unroll
        for (int ht = 0; ht < 8; ++ht)
            uc[ht] = u1f[(size_t)n * 128 + ht * 16 + li] * C2LOG2E;

        // ---- z_ staging, SPLIT per mt-half to cap register pressure:
        //      load 8 x f32x4 (32 regs) -> cvt (zf dies) -> fence -> repeat.
        bf16x8 az[2][4];
        {
            f32x4 zf[4][2];
#pragma unroll
            for (int kb = 0; kb < 4; ++kb) {
                const float* src = zn + ((size_t)n * 32 + li) * 128 + kb * 32 + g * 8;
                zf[kb][0] = *(const f32x4*)(src);
                zf[kb][1] = *(const f32x4*)(src + 4);
            }
#pragma unroll
            for (int kb = 0; kb < 4; ++kb) az[0][kb] = cvt8(zf[kb][0], zf[kb][1]);
        }
        // keep the scheduler from hoisting mt=1 loads above the mt=0 convert
        // (that hoist is exactly what recreated the 64-reg batch and spilled)
        __builtin_amdgcn_sched_barrier(0);
        {
            f32x4 zf[4][2];
#pragma unroll
            for (int kb = 0; kb < 4; ++kb) {
                const float* src = zn + ((size_t)n * 32 + 16 + li) * 128 + kb * 32 + g * 8;
                zf[kb][0] = *(const f32x4*)(src);
                zf[kb][1] = *(const f32x4*)(src + 4);
            }
#pragma unroll
            for (int kb = 0; kb < 4; ++kb) az[1][kb] = cvt8(zf[kb][0], zf[kb][1]);
        }

        // ---- L1: D1[m][h] over z_-half, weights streamed from pw1 ----
        f32x4 acc1[2][8];
#pragma unroll
        for (int mt = 0; mt < 2; ++mt)
#pragma unroll
            for (int ht = 0; ht < 8; ++ht) acc1[mt][ht] = vzero;

#pragma unroll
        for (int kb = 0; kb < 4; ++kb)
#pragma unroll
            for (int ht = 0; ht < 8; ++ht) {
                bf16x8 wf = *(const bf16x8*)(pw1 + (size_t)((kb * 8 + ht) * 64 + lane) * 8);
                acc1[0][ht] = MFMA(az[0][kb], wf, acc1[0][ht]);
                acc1[1][ht] = MFMA(az[1][kb], wf, acc1[1][ht]);
            }

        // ---- phase B: tanh(acc1 + u1) -> wave-private LDS (L2 A-frag) ----
        // value (mt,ht,r): m = mt*16 + g*4 + r, h = ht*16 + li.
        // consumer frag (mt*4 + ht>>1), lane lc = ((ht&1)*2 + (li>>3))*16 + g*4 + r,
        // j = li&7  ->  byte = (frag*64 + lc)*16 + j*2.
#pragma unroll
        for (int mt = 0; mt < 2; ++mt)
#pragma unroll
            for (int ht = 0; ht < 8; ++ht) {
                int fragbase = ((mt * 4 + (ht >> 1)) * 64 + ((ht & 1) * 2 + (li >> 3)) * 16 + g * 4) * 16
                               + (li & 7) * 2;
#pragma unroll
                for (int r = 0; r < 4; ++r) {
                    float v = fast_tanh_fb(acc1[mt][ht][r], uc[ht]);
                    *(bf16*)(aflds + fragbase + r * 16) = (bf16)v;
                }
            }

        // ---- L2: D2[m][o], a1 from LDS frags, weights from pw2 ----
        f32x4 acc2[2][8];
#pragma unroll
        for (int mt = 0; mt < 2; ++mt)
#pragma unroll
            for (int ot = 0; ot < 8; ++ot) acc2[mt][ot] = vzero;

#pragma unroll
        for (int kbh = 0; kbh < 4; ++kbh) {
            bf16x8 a0 = *(const bf16x8*)(aflds + (size_t)((0 + kbh) * 64 + lane) * 16);
            bf16x8 a1 = *(const bf16x8*)(aflds + (size_t)((4 + kbh) * 64 + lane) * 16);
#pragma unroll
            for (int ot = 0; ot < 8; ++ot) {
                bf16x8 wf = *(const bf16x8*)(pw2 + (size_t)((kbh * 8 + ot) * 64 + lane) * 8);
                acc2[0][ot] = MFMA(a0, wf, acc2[0][ot]);
                acc2[1][ot] = MFMA(a1, wf, acc2[1][ot]);
            }
        }

        // ---- phase D: k-sum of tanh over 32 rows = 32 - 2*sum(rpart) ----
#pragma unroll
        for (int ot = 0; ot < 8; ++ot) {
            float s = 0.f;
#pragma unroll
            for (int mt = 0; mt < 2; ++mt)
#pragma unroll
                for (int r = 0; r < 4; ++r)
                    s += tanh_rpart(acc2[mt][ot][r], bc2[ot]);
            s += __shfl_xor(s, 16);
            s += __shfl_xor(s, 32);
            if (lane < 16) {
                float v = __builtin_fmaf(-2.f, s, 32.f);
                feat[(size_t)n * 256 + 128 + ot * 16 + li] = (bf16)v;
            }
        }
    }
}

// ---------------------------------------------------------------------------
// Kernel A: cur branch (feat[:,0:128]) + u1 = z @ nw1[:,:128]^T + nb1.
// ---------------------------------------------------------------------------
__global__ __launch_bounds__(256, 2) void cur_kernel(
    const float* __restrict__ z,
    const float* __restrict__ w1, const float* __restrict__ b1,
    const float* __restrict__ w2, const float* __restrict__ b2,
    const float* __restrict__ nw1, const float* __restrict__ nb1,
    bf16* __restrict__ feat, float* __restrict__ u1, int N)
{
    __shared__ char z_lds[64 * 256];
    __shared__ char h1_lds[64 * 256];

    const int t = threadIdx.x;
    const int wv = t >> 6, lane = t & 63, g = lane >> 4, li = lane & 15;
    const int hbase = wv * 32;
    const int n0 = blockIdx.x * 64;

    bf16x8 w1f[2][4], w2f[2][4], wzf[2][4];
#pragma unroll
    for (int ht = 0; ht < 2; ++ht)
#pragma unroll
        for (int kb = 0; kb < 4; ++kb) {
            const float* p1 = w1 + (size_t)(hbase + 16*ht + li) * 128 + kb*32 + 8*g;
            w1f[ht][kb] = cvt8(*(const f32x4*)p1, *(const f32x4*)(p1 + 4));
            const float* p2 = w2 + (size_t)(hbase + 16*ht + li) * 128 + kb*32 + 8*g;
            w2f[ht][kb] = cvt8(*(const f32x4*)p2, *(const f32x4*)(p2 + 4));
            const float* p3 = nw1 + (size_t)(hbase + 16*ht + li) * 256 + kb*32 + 8*g;
            wzf[ht][kb] = cvt8(*(const f32x4*)p3, *(const f32x4*)(p3 + 4));
        }
    float b1v[2][4], b2v[2][4], bnv[2][4];
#pragma unroll
    for (int ht = 0; ht < 2; ++ht)
#pragma unroll
        for (int rr = 0; rr < 4; ++rr) {
            b1v[ht][rr] = b1[hbase + 16*ht + 4*g + rr];
            b2v[ht][rr] = b2[hbase + 16*ht + 4*g + rr];
            bnv[ht][rr] = nb1[hbase + 16*ht + 4*g + rr];
        }

    {
        int m = t >> 2;
        int c0 = (t & 3) * 32;
        int row = n0 + m; if (row > N - 1) row = N - 1;
        const float* src = z + (size_t)row * 128 + c0;
#pragma unroll
        for (int q = 0; q < 4; ++q) {
            f32x4 a = *(const f32x4*)(src + 8*q);
            f32x4 b = *(const f32x4*)(src + 8*q + 4);
            *(bf16x8*)(z_lds + swz128(m, c0 + 8*q)) = cvt8(a, b);
        }
    }
    __syncthreads();

    const f32x4 vzero = {0.f, 0.f, 0.f, 0.f};
    f32x4 acc1[2][4], accz[2][4];
#pragma unroll
    for (int a = 0; a < 2; ++a)
#pragma unroll
        for (int b = 0; b < 4; ++b) { acc1[a][b] = vzero; accz[a][b] = vzero; }

#pragma unroll
    for (int kb = 0; kb < 4; ++kb) {
        bf16x8 bz[4];
#pragma unroll
        for (int mt = 0; mt < 4; ++mt)
            bz[mt] = *(const bf16x8*)(z_lds + swz128(16*mt + li, kb*32 + 8*g));
#pragma unroll
        for (int ht = 0; ht < 2; ++ht)
#pragma unroll
            for (int mt = 0; mt < 4; ++mt) {
                acc1[ht][mt] = MFMA(w1f[ht][kb], bz[mt], acc1[ht][mt]);
                accz[ht][mt] = MFMA(wzf[ht][kb], bz[mt], accz[ht][mt]);
            }
    }

#pragma unroll
    for (int ht = 0; ht < 2; ++ht)
#pragma unroll
        for (int mt = 0; mt < 4; ++mt) {
            int row = n0 + 16*mt + li;
            if (row < N) {
                f32x4 v;
#pragma unroll
                for (int rr = 0; rr < 4; ++rr) v[rr] = accz[ht][mt][rr] + bnv[ht][rr];
                *(f32x4*)(u1 + (size_t)row * 128 + hbase + 16*ht + 4*g) = v;
            }
        }

#pragma unroll
    for (int ht = 0; ht < 2; ++ht)
#pragma unroll
        for (int mt = 0; mt < 4; ++mt) {
            float v0 = fast_tanh(acc1[ht][mt][0] + b1v[ht][0]);
            float v1 = fast_tanh(acc1[ht][mt][1] + b1v[ht][1]);
            float v2 = fast_tanh(acc1[ht][mt][2] + b1v[ht][2]);
            float v3 = fast_tanh(acc1[ht][mt][3] + b1v[ht][3]);
            int m = 16*mt + li;
            int h = hbase + 16*ht + 4*g;
            st_pair(h1_lds, swz128(m, h),     v0, v1);
            st_pair(h1_lds, swz128(m, h + 2), v2, v3);
        }
    __syncthreads();

    f32x4 acc2[2][4];
#pragma unroll
    for (int a = 0; a < 2; ++a)
#pragma unroll
        for (int b = 0; b < 4; ++b) acc2[a][b] = vzero;

#pragma unroll
    for (int kb = 0; kb < 4; ++kb) {
        bf16x8 bh[4];
#pragma unroll
        for (int mt = 0; mt < 4; ++mt)
            bh[mt] = *(const bf16x8*)(h1_lds + swz128(16*mt + li, kb*32 + 8*g));
#pragma unroll
        for (int ht = 0; ht < 2; ++ht)
#pragma unroll
            for (int mt = 0; mt < 4; ++mt)
                acc2[ht][mt] = MFMA(w2f[ht][kb], bh[mt], acc2[ht][mt]);
    }
#pragma unroll
    for (int ht = 0; ht < 2; ++ht)
#pragma unroll
        for (int mt = 0; mt < 4; ++mt) {
            float v0 = fast_tanh(acc2[ht][mt][0] + b2v[ht][0]);
            float v1 = fast_tanh(acc2[ht][mt][1] + b2v[ht][1]);
            float v2 = fast_tanh(acc2[ht][mt][2] + b2v[ht][2]);
            float v3 = fast_tanh(acc2[ht][mt][3] + b2v[ht][3]);
            int row = n0 + 16*mt + li;
            if (row < N) {
                int h = hbase + 16*ht + 4*g;
                bf16* dst = feat + (size_t)row * 256 + h;
                bf16x2 p01 = {(bf16)v0, (bf16)v1};
                bf16x2 p23 = {(bf16)v2, (bf16)v3};
                *(bf16x2*)(dst)     = p01;
                *(bf16x2*)(dst + 2) = p23;
            }
        }
}

// ---------------------------------------------------------------------------
// Kernel C: dc = feat[N,256] @ ow^T + ob -> f32 out. 64 rows/block.
// ---------------------------------------------------------------------------
__global__ __launch_bounds__(256, 2) void out_kernel(
    const bf16* __restrict__ feat,
    const float* __restrict__ ow, const float* __restrict__ ob,
    float* __restrict__ out, int N)
{
    __shared__ char f_lds[64 * 512];

    const int t = threadIdx.x, wv = t >> 6, lane = t & 63, g = lane >> 4, li = lane & 15;
    const int cbase = wv * 16;
    const int n0 = blockIdx.x * 64;

    bf16x8 owf[8];
#pragma unroll
    for (int kb = 0; kb < 8; ++kb) {
        const float* p = ow + (size_t)(cbase + li) * 256 + kb*32 + 8*g;
        owf[kb] = cvt8(*(const f32x4*)p, *(const f32x4*)(p + 4));
    }
    float obv = ob[cbase + li];

    {
        int m = t >> 2;
        int c0 = (t & 3) * 64;
        int row = n0 + m; if (row > N - 1) row = N - 1;
        const bf16* src = feat + (size_t)row * 256 + c0;
#pragma unroll
        for (int q = 0; q < 8; ++q)
            *(bf16x8*)(f_lds + swz256(m, c0 + 8*q)) = *(const bf16x8*)(src + 8*q);
    }
    __syncthreads();

    const f32x4 vzero = {0.f, 0.f, 0.f, 0.f};
    f32x4 acc[4];
#pragma unroll
    for (int a = 0; a < 4; ++a) acc[a] = vzero;

#pragma unroll
    for (int kb = 0; kb < 8; ++kb) {
        bf16x8 af[4];
#pragma unroll
        for (int mt = 0; mt < 4; ++mt)
            af[mt] = *(const bf16x8*)(f_lds + swz256(16*mt + li, kb*32 + 8*g));
#pragma unroll
        for (int mt = 0; mt < 4; ++mt)
            acc[mt] = MFMA(af[mt], owf[kb], acc[mt]);
    }
#pragma unroll
    for (int mt = 0; mt < 4; ++mt)
#pragma unroll
        for (int rr = 0; rr < 4; ++rr) {
            int row = n0 + 16*mt + 4*g + rr;
            if (row < N) out[(size_t)row * 64 + cbase + li] = acc[mt][rr] + obv;
        }
}

// ---------------------------------------------------------------------------
extern "C" void kernel_launch(void* const* d_in, const int* in_sizes, int n_in,
                              void* d_out, int out_size, void* d_ws, size_t ws_size,
                              hipStream_t stream) {
    const float* z   = (const float*)d_in[0];
    const float* zn  = (const float*)d_in[1];
    const float* cw1 = (const float*)d_in[2];
    const float* cb1 = (const float*)d_in[3];
    const float* cw2 = (const float*)d_in[4];
    const float* cb2 = (const float*)d_in[5];
    const float* nw1 = (const float*)d_in[6];
    const float* nb1 = (const float*)d_in[7];
    const float* nw2 = (const float*)d_in[8];
    const float* nb2 = (const float*)d_in[9];
    const float* ow  = (const float*)d_in[10];
    const float* ob  = (const float*)d_in[11];
    float* out = (float*)d_out;

    const int N = in_sizes[0] / 128;           // 20000
    const int nblk = (N + 63) / 64;            // 313

    char* ws = (char*)d_ws;
    bf16*  feat = (bf16*)ws;                                   // [N][256] bf16
    float* u1   = (float*)(ws + (size_t)N * 256 * sizeof(bf16)); // [N][128] f32
    bf16*  pw1  = (bf16*)(ws + (size_t)N * 256 * sizeof(bf16) + (size_t)N * 128 * sizeof(float));
    bf16*  pw2  = pw1 + 2048 * 8;              // 32 KB each

    (void)n_in; (void)out_size; (void)ws_size;

    prep_kernel<<<8, 256, 0, stream>>>(nw1, nw2, pw1, pw2);
    cur_kernel<<<nblk, 256, 0, stream>>>(z, cw1, cb1, cw2, cb2, nw1, nb1, feat, u1, N);
    nbr_kernel<<<512, 256, 0, stream>>>(zn, u1, pw1, pw2, nb2, feat, N);
    out_kernel<<<nblk, 256, 0, stream>>>(feat, ow, ob, out, N);
}

// Round 9
// 177.752 us; speedup vs baseline: 2.3832x; 1.3842x over previous
//
#include <hip/hip_runtime.h>

// ---------------------------------------------------------------------------
// MLP-GNN fused op for MI355X (gfx950).
//   v  = tanh(tanh(z @ cw1^T + cb1) @ cw2^T + cb2)                    [N,128]
//   vn = tanh(tanh([z|z_] @ nw1^T + nb1) @ nw2^T + nb2).sum(axis=K)   [N,128]
//   dc = [v | vn] @ ow^T + ob                                         [N,64]
// R9: back to the barrier architecture (R3's 126 us, zero scratch), scaled up:
//   nbr_kernel = 512 threads (8 waves, 2 rowgrp x 4 colgrp), tile = 4 n
//   (128 z_ rows) per iteration, 2 raw barriers/iter (1/2n vs R3's 1/n).
//   Weights streamed per-kb from frag-linear pw1/pw2 (L2-resident, reg-live
//   8) so peak arch regs ~115 << the (512,2) budget of 256 -> no spills.
//   u1 prefetch issued BEFORE z prefetch so its counted vmcnt wait does not
//   drain the z loads. cur/out/prep unchanged (proven).
// ---------------------------------------------------------------------------

typedef __bf16 bf16;
typedef __bf16 bf16x2 __attribute__((ext_vector_type(2)));
typedef __bf16 bf16x8 __attribute__((ext_vector_type(8)));
typedef float  f32x4  __attribute__((ext_vector_type(4)));

#define MFMA(a, b, c) __builtin_amdgcn_mfma_f32_16x16x32_bf16((a), (b), (c), 0, 0, 0)

#define C2LOG2E 2.885390081777927f   // 2*log2(e)

// Workgroup barrier WITHOUT the vmcnt(0) drain __syncthreads() implies:
// global loads issued before it stay in flight across the barrier.
__device__ __forceinline__ void block_sync_lds() {
    asm volatile("s_waitcnt lgkmcnt(0)\n\ts_barrier" ::: "memory");
}

// tanh(x) = 1 - 2/(exp2(2*log2e*x)+1) — all signs, inf-safe.
__device__ __forceinline__ float fast_tanh(float x) {
    float t = __builtin_amdgcn_exp2f(x * C2LOG2E);
    return 1.0f - 2.0f * __builtin_amdgcn_rcpf(t + 1.0f);
}
// tanh(acc + u) with pre-scaled bias uc = u*C2LOG2E.
__device__ __forceinline__ float fast_tanh_fb(float acc, float uc) {
    float t = __builtin_amdgcn_exp2f(__builtin_fmaf(acc, C2LOG2E, uc));
    return 1.0f - 2.0f * __builtin_amdgcn_rcpf(t + 1.0f);
}
// r-part only: rcp(exp2(fma)+1); caller uses sum = count - 2*sum(r).
__device__ __forceinline__ float tanh_rpart(float acc, float uc) {
    float t = __builtin_amdgcn_exp2f(__builtin_fmaf(acc, C2LOG2E, uc));
    return __builtin_amdgcn_rcpf(t + 1.0f);
}

__device__ __forceinline__ bf16x8 cvt8(f32x4 a, f32x4 b) {
    bf16x8 r;
    r[0] = (bf16)a[0]; r[1] = (bf16)a[1]; r[2] = (bf16)a[2]; r[3] = (bf16)a[3];
    r[4] = (bf16)b[0]; r[5] = (bf16)b[1]; r[6] = (bf16)b[2]; r[7] = (bf16)b[3];
    return r;
}

// LDS tiles: 128-bf16 rows (256 B = 16 chunks), chunk-XOR swizzle.
__device__ __forceinline__ int swz128(int row, int col) {
    int c = (col >> 3) ^ (row & 15);
    return row * 256 + c * 16 + (col & 7) * 2;
}
__device__ __forceinline__ int swz256(int row, int col) {
    int c = (col >> 3) ^ (row & 15);
    return row * 512 + c * 16 + (col & 7) * 2;
}

__device__ __forceinline__ void st_pair(char* base, int off, float a, float b) {
    bf16x2 p = {(bf16)a, (bf16)b};
    *(bf16x2*)(base + off) = p;
}

// ---------------------------------------------------------------------------
// prep_kernel: weights -> fragment-linear bf16 (one coalesced 16B load/frag).
// pw1 tile (kb,ht): lane l holds w1[ht*16+(l&15)][128+kb*32+(l>>4)*8+j].
// pw2 tile (kbh,ot): lane l holds w2[ot*16+(l&15)][kbh*32+(l>>4)*8+j].
// ---------------------------------------------------------------------------
__global__ void prep_kernel(const float* __restrict__ w1,
                            const float* __restrict__ w2,
                            bf16* __restrict__ pw1, bf16* __restrict__ pw2) {
    int s = blockIdx.x * blockDim.x + threadIdx.x;   // 0..2047
    int lane = s & 63, tile = s >> 6;                // tile 0..31
    int li = lane & 15, g = lane >> 4;
    {
        int kb = tile >> 3, ht = tile & 7;
        const float* src = w1 + (size_t)(ht * 16 + li) * 256 + 128 + kb * 32 + g * 8;
        bf16x8 v;
#pragma unroll
        for (int j = 0; j < 8; ++j) v[j] = (bf16)src[j];
        *(bf16x8*)(pw1 + (size_t)s * 8) = v;
    }
    {
        int kbh = tile >> 3, ot = tile & 7;
        const float* src = w2 + (size_t)(ot * 16 + li) * 128 + kbh * 32 + g * 8;
        bf16x8 v;
#pragma unroll
        for (int j = 0; j < 8; ++j) v[j] = (bf16)src[j];
        *(bf16x8*)(pw2 + (size_t)s * 8) = v;
    }
}

// ---------------------------------------------------------------------------
// nbr_kernel: 512 threads, 8 waves = 2 rowgroups x 4 colgroups.
// Tile = 4 n = 128 z_ rows. Wave owns 64 rows x 32 cols per layer.
// ---------------------------------------------------------------------------
__global__ __launch_bounds__(512, 2) void nbr_kernel(
    const float* __restrict__ zn, const float* __restrict__ u1f,
    const bf16* __restrict__ pw1, const bf16* __restrict__ pw2,
    const float* __restrict__ b2, bf16* __restrict__ feat, int NT)
{
    __shared__ char zc_lds[128 * 256];   // 32 KB, z_ tile (bf16, swizzled)
    __shared__ char h1_lds[128 * 256];   // 32 KB, L1 activations

    const int t = threadIdx.x, wv = t >> 6, lane = t & 63;
    const int li = lane & 15, g = lane >> 4;
    const int rg = wv >> 2;              // 0..1: row group (64 rows)
    const int cg = wv & 3;               // 0..3: col group (32 cols)

    // pre-scaled L2 bias for this wave's two out-col tiles
    float bc2[2];
#pragma unroll
    for (int ht = 0; ht < 2; ++ht) bc2[ht] = b2[cg * 32 + 16 * ht + li] * C2LOG2E;

    // staging geometry: thread stages row srow, cols scol..scol+31 (8 f32x4)
    const int srow = t >> 2;
    const int scol = (t & 3) * 32;
    const int stride = gridDim.x;

    f32x4 rA[8];
    {   // prologue: load tile T0 (grid 256 <= NT=5000, always valid)
        const float* src = zn + ((size_t)blockIdx.x * 128 + srow) * 128 + scol;
#pragma unroll
        for (int q = 0; q < 8; ++q) rA[q] = *(const f32x4*)(src + 4 * q);
    }

    const f32x4 vzero = {0.f, 0.f, 0.f, 0.f};

    for (int T = blockIdx.x; T < NT; T += stride) {
        // ---- write staged tile to LDS (counted vmcnt waits on rA) ----
#pragma unroll
        for (int c2 = 0; c2 < 2; ++c2) {
            bf16x8 v0 = cvt8(rA[c2 * 4 + 0], rA[c2 * 4 + 1]);
            bf16x8 v1 = cvt8(rA[c2 * 4 + 2], rA[c2 * 4 + 3]);
            *(bf16x8*)(zc_lds + swz128(srow, scol + c2 * 16))     = v0;
            *(bf16x8*)(zc_lds + swz128(srow, scol + c2 * 16 + 8)) = v1;
        }
        block_sync_lds();   // B1 (no vmcnt drain)

        // ---- u1 prefetch FIRST (so its vmcnt wait doesn't drain rA) ----
        float uu[2][2];   // [n-local within rowgroup][ht], pre-scaled
#pragma unroll
        for (int ntl = 0; ntl < 2; ++ntl)
#pragma unroll
            for (int ht = 0; ht < 2; ++ht)
                uu[ntl][ht] = u1f[(size_t)(T * 4 + rg * 2 + ntl) * 128
                                  + cg * 32 + 16 * ht + li] * C2LOG2E;

        // ---- z_ prefetch for tile T+stride (in flight across B2/B1) ----
        const int Tn = T + stride;
        if (Tn < NT) {
            const float* src = zn + ((size_t)Tn * 128 + srow) * 128 + scol;
#pragma unroll
            for (int q = 0; q < 8; ++q) rA[q] = *(const f32x4*)(src + 4 * q);
        }

        // ---- L1: D[m][h] over z_-half; weights streamed from pw1 ----
        f32x4 acc1[4][2];
#pragma unroll
        for (int mt = 0; mt < 4; ++mt)
#pragma unroll
            for (int ht = 0; ht < 2; ++ht) acc1[mt][ht] = vzero;

#pragma unroll
        for (int kb = 0; kb < 4; ++kb) {
            bf16x8 a[4];
#pragma unroll
            for (int mt = 0; mt < 4; ++mt)
                a[mt] = *(const bf16x8*)(zc_lds + swz128(rg * 64 + 16 * mt + li, kb * 32 + 8 * g));
            bf16x8 wf[2];
#pragma unroll
            for (int ht = 0; ht < 2; ++ht)
                wf[ht] = *(const bf16x8*)(pw1 + (size_t)((kb * 8 + cg * 2 + ht) * 64 + lane) * 8);
#pragma unroll
            for (int mt = 0; mt < 4; ++mt)
#pragma unroll
                for (int ht = 0; ht < 2; ++ht)
                    acc1[mt][ht] = MFMA(a[mt], wf[ht], acc1[mt][ht]);
        }

        // ---- L1 finish: tanh(acc + u1) -> h1_lds ----
        // value (mt,ht,r): m = rg*64 + 16mt + g*4 + r, h = cg*32 + 16ht + li.
        // n-local = mt>>1 (16mt + g*4 + r < 32 for mt in {0,1} etc.)
#pragma unroll
        for (int mt = 0; mt < 4; ++mt) {
            const int ntl = mt >> 1;
#pragma unroll
            for (int ht = 0; ht < 2; ++ht) {
                const int m0 = rg * 64 + 16 * mt + g * 4;
                const int h  = cg * 32 + 16 * ht + li;
#pragma unroll
                for (int r = 0; r < 4; ++r) {
                    float v = fast_tanh_fb(acc1[mt][ht][r], uu[ntl][ht]);
                    *(bf16*)(h1_lds + swz128(m0 + r, h)) = (bf16)v;
                }
            }
        }
        block_sync_lds();   // B2 (no vmcnt drain — rA prefetch stays in flight)

        // ---- L2: D[m][o]; A from h1_lds, weights streamed from pw2 ----
        f32x4 acc2[4][2];
#pragma unroll
        for (int mt = 0; mt < 4; ++mt)
#pragma unroll
            for (int ht = 0; ht < 2; ++ht) acc2[mt][ht] = vzero;

#pragma unroll
        for (int kbh = 0; kbh < 4; ++kbh) {
            bf16x8 a[4];
#pragma unroll
            for (int mt = 0; mt < 4; ++mt)
                a[mt] = *(const bf16x8*)(h1_lds + swz128(rg * 64 + 16 * mt + li, kbh * 32 + 8 * g));
            bf16x8 wf[2];
#pragma unroll
            for (int ht = 0; ht < 2; ++ht)
                wf[ht] = *(const bf16x8*)(pw2 + (size_t)((kbh * 8 + cg * 2 + ht) * 64 + lane) * 8);
#pragma unroll
            for (int mt = 0; mt < 4; ++mt)
#pragma unroll
                for (int ht = 0; ht < 2; ++ht)
                    acc2[mt][ht] = MFMA(a[mt], wf[ht], acc2[mt][ht]);
        }

        // ---- finish: k-sum of tanh over each n's 32 rows = 32 - 2*sum(r) ----
#pragma unroll
        for (int ntl = 0; ntl < 2; ++ntl)
#pragma unroll
            for (int ht = 0; ht < 2; ++ht) {
                float s = 0.f;
#pragma unroll
                for (int mt2 = 0; mt2 < 2; ++mt2)
#pragma unroll
                    for (int r = 0; r < 4; ++r)
                        s += tanh_rpart(acc2[ntl * 2 + mt2][ht][r], bc2[ht]);
                s += __shfl_xor(s, 16);
                s += __shfl_xor(s, 32);
                if (lane < 16) {
                    float v = __builtin_fmaf(-2.f, s, 32.f);
                    feat[(size_t)(T * 4 + rg * 2 + ntl) * 256 + 128
                         + cg * 32 + 16 * ht + li] = (bf16)v;
                }
            }
        // zc writes of iter i+1 sit behind B2(i); h1 writes of iter i+1 sit
        // behind B1(i+1), which all waves reach only after their L2(i) reads
        // retired -> 2 barriers/iter suffice.
    }
}

// ---------------------------------------------------------------------------
// Kernel A: cur branch (feat[:,0:128]) + u1 = z @ nw1[:,:128]^T + nb1.
// ---------------------------------------------------------------------------
__global__ __launch_bounds__(256, 2) void cur_kernel(
    const float* __restrict__ z,
    const float* __restrict__ w1, const float* __restrict__ b1,
    const float* __restrict__ w2, const float* __restrict__ b2,
    const float* __restrict__ nw1, const float* __restrict__ nb1,
    bf16* __restrict__ feat, float* __restrict__ u1, int N)
{
    __shared__ char z_lds[64 * 256];
    __shared__ char h1_lds[64 * 256];

    const int t = threadIdx.x;
    const int wv = t >> 6, lane = t & 63, g = lane >> 4, li = lane & 15;
    const int hbase = wv * 32;
    const int n0 = blockIdx.x * 64;

    bf16x8 w1f[2][4], w2f[2][4], wzf[2][4];
#pragma unroll
    for (int ht = 0; ht < 2; ++ht)
#pragma unroll
        for (int kb = 0; kb < 4; ++kb) {
            const float* p1 = w1 + (size_t)(hbase + 16*ht + li) * 128 + kb*32 + 8*g;
            w1f[ht][kb] = cvt8(*(const f32x4*)p1, *(const f32x4*)(p1 + 4));
            const float* p2 = w2 + (size_t)(hbase + 16*ht + li) * 128 + kb*32 + 8*g;
            w2f[ht][kb] = cvt8(*(const f32x4*)p2, *(const f32x4*)(p2 + 4));
            const float* p3 = nw1 + (size_t)(hbase + 16*ht + li) * 256 + kb*32 + 8*g;
            wzf[ht][kb] = cvt8(*(const f32x4*)p3, *(const f32x4*)(p3 + 4));
        }
    float b1v[2][4], b2v[2][4], bnv[2][4];
#pragma unroll
    for (int ht = 0; ht < 2; ++ht)
#pragma unroll
        for (int rr = 0; rr < 4; ++rr) {
            b1v[ht][rr] = b1[hbase + 16*ht + 4*g + rr];
            b2v[ht][rr] = b2[hbase + 16*ht + 4*g + rr];
            bnv[ht][rr] = nb1[hbase + 16*ht + 4*g + rr];
        }

    {
        int m = t >> 2;
        int c0 = (t & 3) * 32;
        int row = n0 + m; if (row > N - 1) row = N - 1;
        const float* src = z + (size_t)row * 128 + c0;
#pragma unroll
        for (int q = 0; q < 4; ++q) {
            f32x4 a = *(const f32x4*)(src + 8*q);
            f32x4 b = *(const f32x4*)(src + 8*q + 4);
            *(bf16x8*)(z_lds + swz128(m, c0 + 8*q)) = cvt8(a, b);
        }
    }
    __syncthreads();

    const f32x4 vzero = {0.f, 0.f, 0.f, 0.f};
    f32x4 acc1[2][4], accz[2][4];
#pragma unroll
    for (int a = 0; a < 2; ++a)
#pragma unroll
        for (int b = 0; b < 4; ++b) { acc1[a][b] = vzero; accz[a][b] = vzero; }

#pragma unroll
    for (int kb = 0; kb < 4; ++kb) {
        bf16x8 bz[4];
#pragma unroll
        for (int mt = 0; mt < 4; ++mt)
            bz[mt] = *(const bf16x8*)(z_lds + swz128(16*mt + li, kb*32 + 8*g));
#pragma unroll
        for (int ht = 0; ht < 2; ++ht)
#pragma unroll
            for (int mt = 0; mt < 4; ++mt) {
                acc1[ht][mt] = MFMA(w1f[ht][kb], bz[mt], acc1[ht][mt]);
                accz[ht][mt] = MFMA(wzf[ht][kb], bz[mt], accz[ht][mt]);
            }
    }

#pragma unroll
    for (int ht = 0; ht < 2; ++ht)
#pragma unroll
        for (int mt = 0; mt < 4; ++mt) {
            int row = n0 + 16*mt + li;
            if (row < N) {
                f32x4 v;
#pragma unroll
                for (int rr = 0; rr < 4; ++rr) v[rr] = accz[ht][mt][rr] + bnv[ht][rr];
                *(f32x4*)(u1 + (size_t)row * 128 + hbase + 16*ht + 4*g) = v;
            }
        }

#pragma unroll
    for (int ht = 0; ht < 2; ++ht)
#pragma unroll
        for (int mt = 0; mt < 4; ++mt) {
            float v0 = fast_tanh(acc1[ht][mt][0] + b1v[ht][0]);
            float v1 = fast_tanh(acc1[ht][mt][1] + b1v[ht][1]);
            float v2 = fast_tanh(acc1[ht][mt][2] + b1v[ht][2]);
            float v3 = fast_tanh(acc1[ht][mt][3] + b1v[ht][3]);
            int m = 16*mt + li;
            int h = hbase + 16*ht + 4*g;
            st_pair(h1_lds, swz128(m, h),     v0, v1);
            st_pair(h1_lds, swz128(m, h + 2), v2, v3);
        }
    __syncthreads();

    f32x4 acc2[2][4];
#pragma unroll
    for (int a = 0; a < 2; ++a)
#pragma unroll
        for (int b = 0; b < 4; ++b) acc2[a][b] = vzero;

#pragma unroll
    for (int kb = 0; kb < 4; ++kb) {
        bf16x8 bh[4];
#pragma unroll
        for (int mt = 0; mt < 4; ++mt)
            bh[mt] = *(const bf16x8*)(h1_lds + swz128(16*mt + li, kb*32 + 8*g));
#pragma unroll
        for (int ht = 0; ht < 2; ++ht)
#pragma unroll
            for (int mt = 0; mt < 4; ++mt)
                acc2[ht][mt] = MFMA(w2f[ht][kb], bh[mt], acc2[ht][mt]);
    }
#pragma unroll
    for (int ht = 0; ht < 2; ++ht)
#pragma unroll
        for (int mt = 0; mt < 4; ++mt) {
            float v0 = fast_tanh(acc2[ht][mt][0] + b2v[ht][0]);
            float v1 = fast_tanh(acc2[ht][mt][1] + b2v[ht][1]);
            float v2 = fast_tanh(acc2[ht][mt][2] + b2v[ht][2]);
            float v3 = fast_tanh(acc2[ht][mt][3] + b2v[ht][3]);
            int row = n0 + 16*mt + li;
            if (row < N) {
                int h = hbase + 16*ht + 4*g;
                bf16* dst = feat + (size_t)row * 256 + h;
                bf16x2 p01 = {(bf16)v0, (bf16)v1};
                bf16x2 p23 = {(bf16)v2, (bf16)v3};
                *(bf16x2*)(dst)     = p01;
                *(bf16x2*)(dst + 2) = p23;
            }
        }
}

// ---------------------------------------------------------------------------
// Kernel C: dc = feat[N,256] @ ow^T + ob -> f32 out. 64 rows/block.
// ---------------------------------------------------------------------------
__global__ __launch_bounds__(256, 2) void out_kernel(
    const bf16* __restrict__ feat,
    const float* __restrict__ ow, const float* __restrict__ ob,
    float* __restrict__ out, int N)
{
    __shared__ char f_lds[64 * 512];

    const int t = threadIdx.x, wv = t >> 6, lane = t & 63, g = lane >> 4, li = lane & 15;
    const int cbase = wv * 16;
    const int n0 = blockIdx.x * 64;

    bf16x8 owf[8];
#pragma unroll
    for (int kb = 0; kb < 8; ++kb) {
        const float* p = ow + (size_t)(cbase + li) * 256 + kb*32 + 8*g;
        owf[kb] = cvt8(*(const f32x4*)p, *(const f32x4*)(p + 4));
    }
    float obv = ob[cbase + li];

    {
        int m = t >> 2;
        int c0 = (t & 3) * 64;
        int row = n0 + m; if (row > N - 1) row = N - 1;
        const bf16* src = feat + (size_t)row * 256 + c0;
#pragma unroll
        for (int q = 0; q < 8; ++q)
            *(bf16x8*)(f_lds + swz256(m, c0 + 8*q)) = *(const bf16x8*)(src + 8*q);
    }
    __syncthreads();

    const f32x4 vzero = {0.f, 0.f, 0.f, 0.f};
    f32x4 acc[4];
#pragma unroll
    for (int a = 0; a < 4; ++a) acc[a] = vzero;

#pragma unroll
    for (int kb = 0; kb < 8; ++kb) {
        bf16x8 af[4];
#pragma unroll
        for (int mt = 0; mt < 4; ++mt)
            af[mt] = *(const bf16x8*)(f_lds + swz256(16*mt + li, kb*32 + 8*g));
#pragma unroll
        for (int mt = 0; mt < 4; ++mt)
            acc[mt] = MFMA(af[mt], owf[kb], acc[mt]);
    }
#pragma unroll
    for (int mt = 0; mt < 4; ++mt)
#pragma unroll
        for (int rr = 0; rr < 4; ++rr) {
            int row = n0 + 16*mt + 4*g + rr;
            if (row < N) out[(size_t)row * 64 + cbase + li] = acc[mt][rr] + obv;
        }
}

// ---------------------------------------------------------------------------
extern "C" void kernel_launch(void* const* d_in, const int* in_sizes, int n_in,
                              void* d_out, int out_size, void* d_ws, size_t ws_size,
                              hipStream_t stream) {
    const float* z   = (const float*)d_in[0];
    const float* zn  = (const float*)d_in[1];
    const float* cw1 = (const float*)d_in[2];
    const float* cb1 = (const float*)d_in[3];
    const float* cw2 = (const float*)d_in[4];
    const float* cb2 = (const float*)d_in[5];
    const float* nw1 = (const float*)d_in[6];
    const float* nb1 = (const float*)d_in[7];
    const float* nw2 = (const float*)d_in[8];
    const float* nb2 = (const float*)d_in[9];
    const float* ow  = (const float*)d_in[10];
    const float* ob  = (const float*)d_in[11];
    float* out = (float*)d_out;

    const int N = in_sizes[0] / 128;           // 20000
    const int NT = N / 4;                      // 5000 tiles of 4 n
    const int nblk = (N + 63) / 64;            // 313

    char* ws = (char*)d_ws;
    bf16*  feat = (bf16*)ws;                                   // [N][256] bf16
    float* u1   = (float*)(ws + (size_t)N * 256 * sizeof(bf16)); // [N][128] f32
    bf16*  pw1  = (bf16*)(ws + (size_t)N * 256 * sizeof(bf16) + (size_t)N * 128 * sizeof(float));
    bf16*  pw2  = pw1 + 2048 * 8;              // 32 KB each

    (void)n_in; (void)out_size; (void)ws_size;

    prep_kernel<<<8, 256, 0, stream>>>(nw1, nw2, pw1, pw2);
    cur_kernel<<<nblk, 256, 0, stream>>>(z, cw1, cb1, cw2, cb2, nw1, nb1, feat, u1, N);
    nbr_kernel<<<256, 512, 0, stream>>>(zn, u1, pw1, pw2, nb2, feat, NT);
    out_kernel<<<nblk, 256, 0, stream>>>(feat, ow, ob, out, N);
}

// Round 10
// 156.667 us; speedup vs baseline: 2.7039x; 1.1346x over previous
//
#include <hip/hip_runtime.h>

// ---------------------------------------------------------------------------
// MLP-GNN fused op for MI355X (gfx950).
//   v  = tanh(tanh(z @ cw1^T + cb1) @ cw2^T + cb2)                    [N,128]
//   vn = tanh(tanh([z|z_] @ nw1^T + nb1) @ nw2^T + nb2).sum(axis=K)   [N,128]
//   dc = [v | vn] @ ow^T + ob                                         [N,64]
// R10: R9's coarse tile (512 thr, 8 waves, 4 n/iter, 2 raw barriers/iter)
// + R3's proven inner loop: PERSISTENT register weights (no per-K L2 loads),
// L1 operand-swapped (D[h][m]) so h1 write-back is one b64 store per (mt,ht),
// u1 bias as f32x4. Grid 512 = 2 blocks/CU (16 waves/CU) so blocks overlap.
// No prep kernel. cur/out unchanged (proven).
// ---------------------------------------------------------------------------

typedef __bf16 bf16;
typedef __bf16 bf16x2 __attribute__((ext_vector_type(2)));
typedef __bf16 bf16x4 __attribute__((ext_vector_type(4)));
typedef __bf16 bf16x8 __attribute__((ext_vector_type(8)));
typedef float  f32x4  __attribute__((ext_vector_type(4)));

#define MFMA(a, b, c) __builtin_amdgcn_mfma_f32_16x16x32_bf16((a), (b), (c), 0, 0, 0)

#define C2LOG2E 2.885390081777927f   // 2*log2(e)

// Workgroup barrier WITHOUT the vmcnt(0) drain __syncthreads() implies:
// global loads issued before it stay in flight across the barrier.
__device__ __forceinline__ void block_sync_lds() {
    asm volatile("s_waitcnt lgkmcnt(0)\n\ts_barrier" ::: "memory");
}

// tanh(x) = 1 - 2/(exp2(2*log2e*x)+1) — all signs, inf-safe.
__device__ __forceinline__ float fast_tanh(float x) {
    float t = __builtin_amdgcn_exp2f(x * C2LOG2E);
    return 1.0f - 2.0f * __builtin_amdgcn_rcpf(t + 1.0f);
}
// tanh(acc + u) with pre-scaled bias uc = u*C2LOG2E.
__device__ __forceinline__ float fast_tanh_fb(float acc, float uc) {
    float t = __builtin_amdgcn_exp2f(__builtin_fmaf(acc, C2LOG2E, uc));
    return 1.0f - 2.0f * __builtin_amdgcn_rcpf(t + 1.0f);
}
// r-part only: rcp(exp2(fma)+1); caller uses sum = count - 2*sum(r).
__device__ __forceinline__ float tanh_rpart(float acc, float uc) {
    float t = __builtin_amdgcn_exp2f(__builtin_fmaf(acc, C2LOG2E, uc));
    return __builtin_amdgcn_rcpf(t + 1.0f);
}

__device__ __forceinline__ bf16x8 cvt8(f32x4 a, f32x4 b) {
    bf16x8 r;
    r[0] = (bf16)a[0]; r[1] = (bf16)a[1]; r[2] = (bf16)a[2]; r[3] = (bf16)a[3];
    r[4] = (bf16)b[0]; r[5] = (bf16)b[1]; r[6] = (bf16)b[2]; r[7] = (bf16)b[3];
    return r;
}

// LDS tiles: 128-bf16 rows (256 B = 16 chunks), chunk-XOR swizzle.
__device__ __forceinline__ int swz128(int row, int col) {
    int c = (col >> 3) ^ (row & 15);
    return row * 256 + c * 16 + (col & 7) * 2;
}
__device__ __forceinline__ int swz256(int row, int col) {
    int c = (col >> 3) ^ (row & 15);
    return row * 512 + c * 16 + (col & 7) * 2;
}

__device__ __forceinline__ void st_pair(char* base, int off, float a, float b) {
    bf16x2 p = {(bf16)a, (bf16)b};
    *(bf16x2*)(base + off) = p;
}

// ---------------------------------------------------------------------------
// nbr_kernel: 512 threads, 8 waves = 2 rowgroups x 4 colgroups.
// Tile = 4 n = 128 z_ rows/iter. Wave owns 64 rows x 32 cols per layer.
// L1 swapped: D[h][m] = sum_k W1[h][k] * zc[m][k]  (weight frag = 1st operand)
// L2 normal:  D[m][o] = sum_k h1[m][k] * W2[o][k]
// ---------------------------------------------------------------------------
__global__ __launch_bounds__(512, 2) void nbr_kernel(
    const float* __restrict__ zn, const float* __restrict__ u1f,
    const float* __restrict__ w1, const float* __restrict__ w2,
    const float* __restrict__ b2, bf16* __restrict__ feat, int NT)
{
    __shared__ char zc_lds[128 * 256];   // 32 KB, z_ tile (bf16, swizzled)
    __shared__ char h1_lds[128 * 256];   // 32 KB, L1 activations

    const int t = threadIdx.x, wv = t >> 6, lane = t & 63;
    const int li = lane & 15, g = lane >> 4;
    const int rg = wv >> 2;              // 0..1: row group (64 rows)
    const int cg = wv & 3;               // 0..3: col group (32 cols)
    const int hb = cg * 32;              // this wave's h/o slice base

    // ---- persistent weight fragments (kernel lifetime, 64 regs) ----
    bf16x8 w1f[2][4];   // A-frag, swapped L1: w1[hb+16ht+li][128 + kb*32+8g..]
#pragma unroll
    for (int ht = 0; ht < 2; ++ht)
#pragma unroll
        for (int kb = 0; kb < 4; ++kb) {
            const float* p = w1 + (size_t)(hb + 16*ht + li) * 256 + 128 + kb*32 + 8*g;
            w1f[ht][kb] = cvt8(*(const f32x4*)p, *(const f32x4*)(p + 4));
        }
    bf16x8 w2f[2][4];   // B-frag, L2: w2[hb+16ht+li][kb*32+8g..]
#pragma unroll
    for (int ht = 0; ht < 2; ++ht)
#pragma unroll
        for (int kb = 0; kb < 4; ++kb) {
            const float* p = w2 + (size_t)(hb + 16*ht + li) * 128 + kb*32 + 8*g;
            w2f[ht][kb] = cvt8(*(const f32x4*)p, *(const f32x4*)(p + 4));
        }
    float bc2[2];       // pre-scaled L2 bias (o = hb + 16ht + li)
#pragma unroll
    for (int ht = 0; ht < 2; ++ht) bc2[ht] = b2[hb + 16*ht + li] * C2LOG2E;

    // staging geometry: thread stages row srow, cols scol..scol+31 (8 f32x4)
    const int srow = t >> 2;
    const int scol = (t & 3) * 32;
    const int stride = gridDim.x;

    f32x4 rA[8];
    f32x4 uu[2][2];     // u1 bias [n-local][ht] (4 consecutive h each)
    {   // prologue (grid 512 <= NT=5000: always valid)
        const int T0 = blockIdx.x;
        const float* src = zn + ((size_t)T0 * 128 + srow) * 128 + scol;
#pragma unroll
        for (int q = 0; q < 8; ++q) rA[q] = *(const f32x4*)(src + 4 * q);
#pragma unroll
        for (int ntl = 0; ntl < 2; ++ntl)
#pragma unroll
            for (int ht = 0; ht < 2; ++ht)
                uu[ntl][ht] = *(const f32x4*)(u1f + (size_t)(T0*4 + rg*2 + ntl) * 128
                                              + hb + 16*ht + 4*g);
    }

    const f32x4 vzero = {0.f, 0.f, 0.f, 0.f};

    for (int T = blockIdx.x; T < NT; T += stride) {
        // ---- write staged tile to LDS (counted vmcnt waits on rA) ----
#pragma unroll
        for (int c2 = 0; c2 < 2; ++c2) {
            bf16x8 v0 = cvt8(rA[c2 * 4 + 0], rA[c2 * 4 + 1]);
            bf16x8 v1 = cvt8(rA[c2 * 4 + 2], rA[c2 * 4 + 3]);
            *(bf16x8*)(zc_lds + swz128(srow, scol + c2 * 16))     = v0;
            *(bf16x8*)(zc_lds + swz128(srow, scol + c2 * 16 + 8)) = v1;
        }
        block_sync_lds();   // B1 (no vmcnt drain)

        // ---- z_ prefetch for tile T+stride (rides across B2/B1) ----
        const int Tn = T + stride;
        if (Tn < NT) {
            const float* src = zn + ((size_t)Tn * 128 + srow) * 128 + scol;
#pragma unroll
            for (int q = 0; q < 8; ++q) rA[q] = *(const f32x4*)(src + 4 * q);
        }

        // ---- L1 (swapped): D[h][m]; weights in regs, zc from LDS ----
        f32x4 acc1[4][2];   // [mt][ht]
#pragma unroll
        for (int mt = 0; mt < 4; ++mt)
#pragma unroll
            for (int ht = 0; ht < 2; ++ht) acc1[mt][ht] = vzero;

        __builtin_amdgcn_s_setprio(1);
#pragma unroll
        for (int kb = 0; kb < 4; ++kb) {
            bf16x8 bz[4];
#pragma unroll
            for (int mt = 0; mt < 4; ++mt)
                bz[mt] = *(const bf16x8*)(zc_lds + swz128(rg*64 + 16*mt + li, kb*32 + 8*g));
#pragma unroll
            for (int mt = 0; mt < 4; ++mt)
#pragma unroll
                for (int ht = 0; ht < 2; ++ht)
                    acc1[mt][ht] = MFMA(w1f[ht][kb], bz[mt], acc1[mt][ht]);
        }
        __builtin_amdgcn_s_setprio(0);

        // ---- L1 finish: tanh(acc + u1) -> h1_lds (one b64 store each) ----
        // value (mt,ht,r): m = rg*64 + 16mt + li, h = hb + 16ht + 4g + r.
#pragma unroll
        for (int mt = 0; mt < 4; ++mt) {
            const int ntl = mt >> 1;
            const int m = rg*64 + 16*mt + li;
#pragma unroll
            for (int ht = 0; ht < 2; ++ht) {
                f32x4 uc = uu[ntl][ht] * C2LOG2E;
                bf16x4 q;
#pragma unroll
                for (int r = 0; r < 4; ++r)
                    q[r] = (bf16)fast_tanh_fb(acc1[mt][ht][r], uc[r]);
                *(bf16x4*)(h1_lds + swz128(m, hb + 16*ht + 4*g)) = q;
            }
        }

        // ---- refill uu for T+stride (consumed above; full iter of slack) ----
        if (Tn < NT) {
#pragma unroll
            for (int ntl = 0; ntl < 2; ++ntl)
#pragma unroll
                for (int ht = 0; ht < 2; ++ht)
                    uu[ntl][ht] = *(const f32x4*)(u1f + (size_t)(Tn*4 + rg*2 + ntl) * 128
                                                  + hb + 16*ht + 4*g);
        }
        block_sync_lds();   // B2 (no vmcnt drain — prefetches stay in flight)

        // ---- L2 (normal): D[m][o]; h1 from LDS, weights in regs ----
        f32x4 acc2[4][2];
#pragma unroll
        for (int mt = 0; mt < 4; ++mt)
#pragma unroll
            for (int ht = 0; ht < 2; ++ht) acc2[mt][ht] = vzero;

        __builtin_amdgcn_s_setprio(1);
#pragma unroll
        for (int kb = 0; kb < 4; ++kb) {
            bf16x8 ah[4];
#pragma unroll
            for (int mt = 0; mt < 4; ++mt)
                ah[mt] = *(const bf16x8*)(h1_lds + swz128(rg*64 + 16*mt + li, kb*32 + 8*g));
#pragma unroll
            for (int mt = 0; mt < 4; ++mt)
#pragma unroll
                for (int ht = 0; ht < 2; ++ht)
                    acc2[mt][ht] = MFMA(ah[mt], w2f[ht][kb], acc2[mt][ht]);
        }
        __builtin_amdgcn_s_setprio(0);

        // ---- finish: k-sum of tanh over each n's 32 rows = 32 - 2*sum(r) ----
#pragma unroll
        for (int ntl = 0; ntl < 2; ++ntl)
#pragma unroll
            for (int ht = 0; ht < 2; ++ht) {
                float s = 0.f;
#pragma unroll
                for (int mt2 = 0; mt2 < 2; ++mt2)
#pragma unroll
                    for (int r = 0; r < 4; ++r)
                        s += tanh_rpart(acc2[ntl*2 + mt2][ht][r], bc2[ht]);
                s += __shfl_xor(s, 16);
                s += __shfl_xor(s, 32);
                if (lane < 16) {
                    float v = __builtin_fmaf(-2.f, s, 32.f);
                    feat[(size_t)(T*4 + rg*2 + ntl) * 256 + 128 + hb + 16*ht + li] = (bf16)v;
                }
            }
        // zc writes of iter i+1 sit behind B2(i); h1 writes of iter i+1 sit
        // behind B1(i+1) -> 2 barriers/iter suffice.
    }
}

// ---------------------------------------------------------------------------
// Kernel A: cur branch (feat[:,0:128]) + u1 = z @ nw1[:,:128]^T + nb1.
// ---------------------------------------------------------------------------
__global__ __launch_bounds__(256, 2) void cur_kernel(
    const float* __restrict__ z,
    const float* __restrict__ w1, const float* __restrict__ b1,
    const float* __restrict__ w2, const float* __restrict__ b2,
    const float* __restrict__ nw1, const float* __restrict__ nb1,
    bf16* __restrict__ feat, float* __restrict__ u1, int N)
{
    __shared__ char z_lds[64 * 256];
    __shared__ char h1_lds[64 * 256];

    const int t = threadIdx.x;
    const int wv = t >> 6, lane = t & 63, g = lane >> 4, li = lane & 15;
    const int hbase = wv * 32;
    const int n0 = blockIdx.x * 64;

    bf16x8 w1f[2][4], w2f[2][4], wzf[2][4];
#pragma unroll
    for (int ht = 0; ht < 2; ++ht)
#pragma unroll
        for (int kb = 0; kb < 4; ++kb) {
            const float* p1 = w1 + (size_t)(hbase + 16*ht + li) * 128 + kb*32 + 8*g;
            w1f[ht][kb] = cvt8(*(const f32x4*)p1, *(const f32x4*)(p1 + 4));
            const float* p2 = w2 + (size_t)(hbase + 16*ht + li) * 128 + kb*32 + 8*g;
            w2f[ht][kb] = cvt8(*(const f32x4*)p2, *(const f32x4*)(p2 + 4));
            const float* p3 = nw1 + (size_t)(hbase + 16*ht + li) * 256 + kb*32 + 8*g;
            wzf[ht][kb] = cvt8(*(const f32x4*)p3, *(const f32x4*)(p3 + 4));
        }
    float b1v[2][4], b2v[2][4], bnv[2][4];
#pragma unroll
    for (int ht = 0; ht < 2; ++ht)
#pragma unroll
        for (int rr = 0; rr < 4; ++rr) {
            b1v[ht][rr] = b1[hbase + 16*ht + 4*g + rr];
            b2v[ht][rr] = b2[hbase + 16*ht + 4*g + rr];
            bnv[ht][rr] = nb1[hbase + 16*ht + 4*g + rr];
        }

    {
        int m = t >> 2;
        int c0 = (t & 3) * 32;
        int row = n0 + m; if (row > N - 1) row = N - 1;
        const float* src = z + (size_t)row * 128 + c0;
#pragma unroll
        for (int q = 0; q < 4; ++q) {
            f32x4 a = *(const f32x4*)(src + 8*q);
            f32x4 b = *(const f32x4*)(src + 8*q + 4);
            *(bf16x8*)(z_lds + swz128(m, c0 + 8*q)) = cvt8(a, b);
        }
    }
    __syncthreads();

    const f32x4 vzero = {0.f, 0.f, 0.f, 0.f};
    f32x4 acc1[2][4], accz[2][4];
#pragma unroll
    for (int a = 0; a < 2; ++a)
#pragma unroll
        for (int b = 0; b < 4; ++b) { acc1[a][b] = vzero; accz[a][b] = vzero; }

#pragma unroll
    for (int kb = 0; kb < 4; ++kb) {
        bf16x8 bz[4];
#pragma unroll
        for (int mt = 0; mt < 4; ++mt)
            bz[mt] = *(const bf16x8*)(z_lds + swz128(16*mt + li, kb*32 + 8*g));
#pragma unroll
        for (int ht = 0; ht < 2; ++ht)
#pragma unroll
            for (int mt = 0; mt < 4; ++mt) {
                acc1[ht][mt] = MFMA(w1f[ht][kb], bz[mt], acc1[ht][mt]);
                accz[ht][mt] = MFMA(wzf[ht][kb], bz[mt], accz[ht][mt]);
            }
    }

#pragma unroll
    for (int ht = 0; ht < 2; ++ht)
#pragma unroll
        for (int mt = 0; mt < 4; ++mt) {
            int row = n0 + 16*mt + li;
            if (row < N) {
                f32x4 v;
#pragma unroll
                for (int rr = 0; rr < 4; ++rr) v[rr] = accz[ht][mt][rr] + bnv[ht][rr];
                *(f32x4*)(u1 + (size_t)row * 128 + hbase + 16*ht + 4*g) = v;
            }
        }

#pragma unroll
    for (int ht = 0; ht < 2; ++ht)
#pragma unroll
        for (int mt = 0; mt < 4; ++mt) {
            float v0 = fast_tanh(acc1[ht][mt][0] + b1v[ht][0]);
            float v1 = fast_tanh(acc1[ht][mt][1] + b1v[ht][1]);
            float v2 = fast_tanh(acc1[ht][mt][2] + b1v[ht][2]);
            float v3 = fast_tanh(acc1[ht][mt][3] + b1v[ht][3]);
            int m = 16*mt + li;
            int h = hbase + 16*ht + 4*g;
            st_pair(h1_lds, swz128(m, h),     v0, v1);
            st_pair(h1_lds, swz128(m, h + 2), v2, v3);
        }
    __syncthreads();

    f32x4 acc2[2][4];
#pragma unroll
    for (int a = 0; a < 2; ++a)
#pragma unroll
        for (int b = 0; b < 4; ++b) acc2[a][b] = vzero;

#pragma unroll
    for (int kb = 0; kb < 4; ++kb) {
        bf16x8 bh[4];
#pragma unroll
        for (int mt = 0; mt < 4; ++mt)
            bh[mt] = *(const bf16x8*)(h1_lds + swz128(16*mt + li, kb*32 + 8*g));
#pragma unroll
        for (int ht = 0; ht < 2; ++ht)
#pragma unroll
            for (int mt = 0; mt < 4; ++mt)
                acc2[ht][mt] = MFMA(w2f[ht][kb], bh[mt], acc2[ht][mt]);
    }
#pragma unroll
    for (int ht = 0; ht < 2; ++ht)
#pragma unroll
        for (int mt = 0; mt < 4; ++mt) {
            float v0 = fast_tanh(acc2[ht][mt][0] + b2v[ht][0]);
            float v1 = fast_tanh(acc2[ht][mt][1] + b2v[ht][1]);
            float v2 = fast_tanh(acc2[ht][mt][2] + b2v[ht][2]);
            float v3 = fast_tanh(acc2[ht][mt][3] + b2v[ht][3]);
            int row = n0 + 16*mt + li;
            if (row < N) {
                int h = hbase + 16*ht + 4*g;
                bf16* dst = feat + (size_t)row * 256 + h;
                bf16x2 p01 = {(bf16)v0, (bf16)v1};
                bf16x2 p23 = {(bf16)v2, (bf16)v3};
                *(bf16x2*)(dst)     = p01;
                *(bf16x2*)(dst + 2) = p23;
            }
        }
}

// ---------------------------------------------------------------------------
// Kernel C: dc = feat[N,256] @ ow^T + ob -> f32 out. 64 rows/block.
// ---------------------------------------------------------------------------
__global__ __launch_bounds__(256, 2) void out_kernel(
    const bf16* __restrict__ feat,
    const float* __restrict__ ow, const float* __restrict__ ob,
    float* __restrict__ out, int N)
{
    __shared__ char f_lds[64 * 512];

    const int t = threadIdx.x, wv = t >> 6, lane = t & 63, g = lane >> 4, li = lane & 15;
    const int cbase = wv * 16;
    const int n0 = blockIdx.x * 64;

    bf16x8 owf[8];
#pragma unroll
    for (int kb = 0; kb < 8; ++kb) {
        const float* p = ow + (size_t)(cbase + li) * 256 + kb*32 + 8*g;
        owf[kb] = cvt8(*(const f32x4*)p, *(const f32x4*)(p + 4));
    }
    float obv = ob[cbase + li];

    {
        int m = t >> 2;
        int c0 = (t & 3) * 64;
        int row = n0 + m; if (row > N - 1) row = N - 1;
        const bf16* src = feat + (size_t)row * 256 + c0;
#pragma unroll
        for (int q = 0; q < 8; ++q)
            *(bf16x8*)(f_lds + swz256(m, c0 + 8*q)) = *(const bf16x8*)(src + 8*q);
    }
    __syncthreads();

    const f32x4 vzero = {0.f, 0.f, 0.f, 0.f};
    f32x4 acc[4];
#pragma unroll
    for (int a = 0; a < 4; ++a) acc[a] = vzero;

#pragma unroll
    for (int kb = 0; kb < 8; ++kb) {
        bf16x8 af[4];
#pragma unroll
        for (int mt = 0; mt < 4; ++mt)
            af[mt] = *(const bf16x8*)(f_lds + swz256(16*mt + li, kb*32 + 8*g));
#pragma unroll
        for (int mt = 0; mt < 4; ++mt)
            acc[mt] = MFMA(af[mt], owf[kb], acc[mt]);
    }
#pragma unroll
    for (int mt = 0; mt < 4; ++mt)
#pragma unroll
        for (int rr = 0; rr < 4; ++rr) {
            int row = n0 + 16*mt + 4*g + rr;
            if (row < N) out[(size_t)row * 64 + cbase + li] = acc[mt][rr] + obv;
        }
}

// ---------------------------------------------------------------------------
extern "C" void kernel_launch(void* const* d_in, const int* in_sizes, int n_in,
                              void* d_out, int out_size, void* d_ws, size_t ws_size,
                              hipStream_t stream) {
    const float* z   = (const float*)d_in[0];
    const float* zn  = (const float*)d_in[1];
    const float* cw1 = (const float*)d_in[2];
    const float* cb1 = (const float*)d_in[3];
    const float* cw2 = (const float*)d_in[4];
    const float* cb2 = (const float*)d_in[5];
    const float* nw1 = (const float*)d_in[6];
    const float* nb1 = (const float*)d_in[7];
    const float* nw2 = (const float*)d_in[8];
    const float* nb2 = (const float*)d_in[9];
    const float* ow  = (const float*)d_in[10];
    const float* ob  = (const float*)d_in[11];
    float* out = (float*)d_out;

    const int N = in_sizes[0] / 128;           // 20000
    const int NT = N / 4;                      // 5000 tiles of 4 n
    const int nblk = (N + 63) / 64;            // 313

    char* ws = (char*)d_ws;
    bf16*  feat = (bf16*)ws;                                     // [N][256] bf16
    float* u1   = (float*)(ws + (size_t)N * 256 * sizeof(bf16)); // [N][128] f32

    (void)n_in; (void)out_size; (void)ws_size;

    cur_kernel<<<nblk, 256, 0, stream>>>(z, cw1, cb1, cw2, cb2, nw1, nb1, feat, u1, N);
    nbr_kernel<<<512, 512, 0, stream>>>(zn, u1, nw1, nw2, nb2, feat, NT);
    out_kernel<<<nblk, 256, 0, stream>>>(feat, ow, ob, out, N);
}

// Round 11
// 150.376 us; speedup vs baseline: 2.8170x; 1.0418x over previous
//
#include <hip/hip_runtime.h>

// ---------------------------------------------------------------------------
// MLP-GNN fused op for MI355X (gfx950).
//   v  = tanh(tanh(z @ cw1^T + cb1) @ cw2^T + cb2)                    [N,128]
//   vn = tanh(tanh([z|z_] @ nw1^T + nb1) @ nw2^T + nb2).sum(axis=K)   [N,128]
//   dc = [v | vn] @ ow^T + ob                                         [N,64]
// R11: R3's proven fine-grained barrier structure (2n/iter, 256 thr) raised
// to 3 blocks/CU (12 waves/CU) via __launch_bounds__(256,3) + register diet:
//   - z_ staging split into chunk A (n=2p, issued after B1) and chunk B
//     (n=2p+1, issued after L1-finish) -> only 16 staging regs live in L1.
//   - h1 write-back as single bf16x4 stores.
//   Peak unified regs ~165 <= 170 budget (acc in AGPRs, uneven split OK).
// cur/out unchanged (proven). No prep kernel.
// ---------------------------------------------------------------------------

typedef __bf16 bf16;
typedef __bf16 bf16x2 __attribute__((ext_vector_type(2)));
typedef __bf16 bf16x4 __attribute__((ext_vector_type(4)));
typedef __bf16 bf16x8 __attribute__((ext_vector_type(8)));
typedef float  f32x4  __attribute__((ext_vector_type(4)));

#define MFMA(a, b, c) __builtin_amdgcn_mfma_f32_16x16x32_bf16((a), (b), (c), 0, 0, 0)

#define C2LOG2E 2.885390081777927f   // 2*log2(e)

// Workgroup barrier WITHOUT the vmcnt(0) drain __syncthreads() implies:
// global loads issued before it stay in flight across the barrier.
__device__ __forceinline__ void block_sync_lds() {
    asm volatile("s_waitcnt lgkmcnt(0)\n\ts_barrier" ::: "memory");
}

// tanh(x) = 1 - 2/(exp2(2*log2e*x)+1) — all signs, inf-safe.
__device__ __forceinline__ float fast_tanh(float x) {
    float t = __builtin_amdgcn_exp2f(x * C2LOG2E);
    return 1.0f - 2.0f * __builtin_amdgcn_rcpf(t + 1.0f);
}
// tanh(acc + u) with pre-scaled bias uc = u*C2LOG2E.
__device__ __forceinline__ float fast_tanh_fb(float acc, float uc) {
    float t = __builtin_amdgcn_exp2f(__builtin_fmaf(acc, C2LOG2E, uc));
    return 1.0f - 2.0f * __builtin_amdgcn_rcpf(t + 1.0f);
}
// r-part only: rcp(exp2(fma)+1); caller uses sum = count - 2*sum(r).
__device__ __forceinline__ float tanh_rpart(float acc, float uc) {
    float t = __builtin_amdgcn_exp2f(__builtin_fmaf(acc, C2LOG2E, uc));
    return __builtin_amdgcn_rcpf(t + 1.0f);
}

__device__ __forceinline__ bf16x8 cvt8(f32x4 a, f32x4 b) {
    bf16x8 r;
    r[0] = (bf16)a[0]; r[1] = (bf16)a[1]; r[2] = (bf16)a[2]; r[3] = (bf16)a[3];
    r[4] = (bf16)b[0]; r[5] = (bf16)b[1]; r[6] = (bf16)b[2]; r[7] = (bf16)b[3];
    return r;
}

// LDS tiles: 128-bf16 rows (256 B = 16 chunks), chunk-XOR swizzle.
__device__ __forceinline__ int swz128(int row, int col) {
    int c = (col >> 3) ^ (row & 15);
    return row * 256 + c * 16 + (col & 7) * 2;
}
__device__ __forceinline__ int swz256(int row, int col) {
    int c = (col >> 3) ^ (row & 15);
    return row * 512 + c * 16 + (col & 7) * 2;
}

__device__ __forceinline__ void st_pair(char* base, int off, float a, float b) {
    bf16x2 p = {(bf16)a, (bf16)b};
    *(bf16x2*)(base + off) = p;
}

// ---------------------------------------------------------------------------
// nbr_kernel: 256 threads (4 waves), one PAIR (2p, 2p+1) per iteration.
// L1 operand-swapped over the z_-half (bias u1 from cur_kernel); L2 normal;
// k-sum via 2x shfl_xor. 2 raw barriers/iter. 3 blocks/CU.
// ---------------------------------------------------------------------------
__global__ __launch_bounds__(256, 3) void nbr_kernel(
    const float* __restrict__ zn, const float* __restrict__ u1,
    const float* __restrict__ w1, const float* __restrict__ w2,
    const float* __restrict__ b2,
    bf16* __restrict__ feat, int NP)
{
    __shared__ char zc_lds[2][32 * 256];
    __shared__ char h1_lds[2][32 * 256];

    const int t = threadIdx.x;
    const int wv = t >> 6, lane = t & 63, g = lane >> 4, li = lane & 15;
    const int hbase = wv * 32;

    // z_-half of W1 (cols 128..255) as swapped-L1 A-frags (32 regs)
    bf16x8 w1f[2][4];
#pragma unroll
    for (int ht = 0; ht < 2; ++ht)
#pragma unroll
        for (int kb = 0; kb < 4; ++kb) {
            const float* p = w1 + (size_t)(hbase + 16*ht + li) * 256 + 128 + kb*32 + 8*g;
            w1f[ht][kb] = cvt8(*(const f32x4*)p, *(const f32x4*)(p + 4));
        }
    bf16x8 w2f[2][4];   // L2 B-frags (32 regs)
#pragma unroll
    for (int nt = 0; nt < 2; ++nt)
#pragma unroll
        for (int kb = 0; kb < 4; ++kb) {
            const float* p = w2 + (size_t)(hbase + 16*nt + li) * 128 + kb*32 + 8*g;
            w2f[nt][kb] = cvt8(*(const f32x4*)p, *(const f32x4*)(p + 4));
        }
    float bc2[2];       // pre-scaled L2 bias
#pragma unroll
    for (int nt = 0; nt < 2; ++nt) bc2[nt] = b2[hbase + 16*nt + li] * C2LOG2E;

    const int sm  = t >> 3;        // staging row 0..31
    const int scf = (t & 7) * 16;  // staging col (floats)
    const int str = gridDim.x;

    f32x4 rA[4], rB[4];  // chunk A = n 2p, chunk B = n 2p+1 (16 regs each)
    f32x4 uu[2][2];      // u1 bias for the pair

    auto load_chunk = [&](f32x4 (&R)[4], int nidx) {
        const float* src = zn + ((size_t)nidx * 32 + sm) * 128 + scf;
#pragma unroll
        for (int q = 0; q < 4; ++q) R[q] = *(const f32x4*)(src + 4*q);
    };
    auto load_u = [&](int pp) {
#pragma unroll
        for (int j = 0; j < 2; ++j)
#pragma unroll
            for (int ht = 0; ht < 2; ++ht)
                uu[j][ht] = *(const f32x4*)(u1 + (size_t)(2*pp + j) * 128 + hbase + 16*ht + 4*g);
    };

    {
        const int p0 = blockIdx.x;
        load_chunk(rA, 2*p0);
        load_chunk(rB, 2*p0 + 1);
        load_u(p0);
    }

    const f32x4 vzero = {0.f, 0.f, 0.f, 0.f};

    for (int p = blockIdx.x; p < NP; p += str) {
        // ---- write staged pair to LDS (counted vmcnt waits per chunk) ----
        *(bf16x8*)(zc_lds[0] + swz128(sm, scf))     = cvt8(rA[0], rA[1]);
        *(bf16x8*)(zc_lds[0] + swz128(sm, scf + 8)) = cvt8(rA[2], rA[3]);
        *(bf16x8*)(zc_lds[1] + swz128(sm, scf))     = cvt8(rB[0], rB[1]);
        *(bf16x8*)(zc_lds[1] + swz128(sm, scf + 8)) = cvt8(rB[2], rB[3]);
        block_sync_lds();   // B1 (no vmcnt drain)

        const int pp = p + str;
        // ---- issue chunk A of next pair (rides across B2/B1) ----
        if (pp < NP) load_chunk(rA, 2*pp);

        // ---- layer 1 (swapped, z_-half): 32 MFMAs, 8 indep chains ----
        f32x4 acc1[2][2][2];
#pragma unroll
        for (int j = 0; j < 2; ++j)
#pragma unroll
            for (int a = 0; a < 2; ++a)
#pragma unroll
                for (int b = 0; b < 2; ++b) acc1[j][a][b] = vzero;

        __builtin_amdgcn_s_setprio(1);
#pragma unroll
        for (int kb = 0; kb < 4; ++kb) {
            bf16x8 bz[2][2];
#pragma unroll
            for (int j = 0; j < 2; ++j)
#pragma unroll
                for (int mt = 0; mt < 2; ++mt)
                    bz[j][mt] = *(const bf16x8*)(zc_lds[j] + swz128(16*mt + li, kb*32 + 8*g));
#pragma unroll
            for (int j = 0; j < 2; ++j)
#pragma unroll
                for (int ht = 0; ht < 2; ++ht)
#pragma unroll
                    for (int mt = 0; mt < 2; ++mt)
                        acc1[j][ht][mt] = MFMA(w1f[ht][kb], bz[j][mt], acc1[j][ht][mt]);
        }
        __builtin_amdgcn_s_setprio(0);

        // ---- finish L1: tanh(acc + u1) -> h1 (single b64 store each) ----
        // value (j,ht,mt,r): m = 16mt+li, h = hbase+16ht+4g+r
#pragma unroll
        for (int j = 0; j < 2; ++j)
#pragma unroll
            for (int ht = 0; ht < 2; ++ht) {
                f32x4 uc = uu[j][ht] * C2LOG2E;
#pragma unroll
                for (int mt = 0; mt < 2; ++mt) {
                    bf16x4 q;
#pragma unroll
                    for (int r = 0; r < 4; ++r)
                        q[r] = (bf16)fast_tanh_fb(acc1[j][ht][mt][r], uc[r]);
                    *(bf16x4*)(h1_lds[j] + swz128(16*mt + li, hbase + 16*ht + 4*g)) = q;
                }
            }

        // ---- issue chunk B of next pair, then u1 (consumed after B) ----
        if (pp < NP) {
            load_chunk(rB, 2*pp + 1);
            load_u(pp);
        }
        block_sync_lds();   // B2 (no vmcnt drain — prefetches stay in flight)

        // ---- layer 2 (normal): 32 MFMAs, 8 indep chains ----
        f32x4 acc2[2][2][2];
#pragma unroll
        for (int j = 0; j < 2; ++j)
#pragma unroll
            for (int a = 0; a < 2; ++a)
#pragma unroll
                for (int b = 0; b < 2; ++b) acc2[j][a][b] = vzero;

        __builtin_amdgcn_s_setprio(1);
#pragma unroll
        for (int kb = 0; kb < 4; ++kb) {
            bf16x8 ah[2][2];
#pragma unroll
            for (int j = 0; j < 2; ++j)
#pragma unroll
                for (int mt = 0; mt < 2; ++mt)
                    ah[j][mt] = *(const bf16x8*)(h1_lds[j] + swz128(16*mt + li, kb*32 + 8*g));
#pragma unroll
            for (int j = 0; j < 2; ++j)
#pragma unroll
                for (int mt = 0; mt < 2; ++mt)
#pragma unroll
                    for (int nt = 0; nt < 2; ++nt)
                        acc2[j][mt][nt] = MFMA(ah[j][mt], w2f[nt][kb], acc2[j][mt][nt]);
        }
        __builtin_amdgcn_s_setprio(0);

        // ---- finish L2: k-sum of tanh over 32 rows = 32 - 2*sum(r) ----
#pragma unroll
        for (int j = 0; j < 2; ++j) {
            float sr0 = 0.f, sr1 = 0.f;
#pragma unroll
            for (int mt = 0; mt < 2; ++mt)
#pragma unroll
                for (int rr = 0; rr < 4; ++rr) {
                    sr0 += tanh_rpart(acc2[j][mt][0][rr], bc2[0]);
                    sr1 += tanh_rpart(acc2[j][mt][1][rr], bc2[1]);
                }
            sr0 += __shfl_xor(sr0, 16); sr0 += __shfl_xor(sr0, 32);
            sr1 += __shfl_xor(sr1, 16); sr1 += __shfl_xor(sr1, 32);
            if (lane < 16) {
                float s0 = __builtin_fmaf(-2.f, sr0, 32.f);
                float s1 = __builtin_fmaf(-2.f, sr1, 32.f);
                bf16* dst = feat + (size_t)(2*p + j) * 256 + 128 + hbase + lane;
                dst[0]  = (bf16)s0;
                dst[16] = (bf16)s1;
            }
        }
        // zc writes of iter i+1 sit behind B2(i); h1 writes of iter i+1 sit
        // behind B1(i+1) -> 2 barriers/iter suffice.
    }
}

// ---------------------------------------------------------------------------
// Kernel A: cur branch (feat[:,0:128]) + u1 = z @ nw1[:,:128]^T + nb1.
// ---------------------------------------------------------------------------
__global__ __launch_bounds__(256, 2) void cur_kernel(
    const float* __restrict__ z,
    const float* __restrict__ w1, const float* __restrict__ b1,
    const float* __restrict__ w2, const float* __restrict__ b2,
    const float* __restrict__ nw1, const float* __restrict__ nb1,
    bf16* __restrict__ feat, float* __restrict__ u1, int N)
{
    __shared__ char z_lds[64 * 256];
    __shared__ char h1_lds[64 * 256];

    const int t = threadIdx.x;
    const int wv = t >> 6, lane = t & 63, g = lane >> 4, li = lane & 15;
    const int hbase = wv * 32;
    const int n0 = blockIdx.x * 64;

    bf16x8 w1f[2][4], w2f[2][4], wzf[2][4];
#pragma unroll
    for (int ht = 0; ht < 2; ++ht)
#pragma unroll
        for (int kb = 0; kb < 4; ++kb) {
            const float* p1 = w1 + (size_t)(hbase + 16*ht + li) * 128 + kb*32 + 8*g;
            w1f[ht][kb] = cvt8(*(const f32x4*)p1, *(const f32x4*)(p1 + 4));
            const float* p2 = w2 + (size_t)(hbase + 16*ht + li) * 128 + kb*32 + 8*g;
            w2f[ht][kb] = cvt8(*(const f32x4*)p2, *(const f32x4*)(p2 + 4));
            const float* p3 = nw1 + (size_t)(hbase + 16*ht + li) * 256 + kb*32 + 8*g;
            wzf[ht][kb] = cvt8(*(const f32x4*)p3, *(const f32x4*)(p3 + 4));
        }
    float b1v[2][4], b2v[2][4], bnv[2][4];
#pragma unroll
    for (int ht = 0; ht < 2; ++ht)
#pragma unroll
        for (int rr = 0; rr < 4; ++rr) {
            b1v[ht][rr] = b1[hbase + 16*ht + 4*g + rr];
            b2v[ht][rr] = b2[hbase + 16*ht + 4*g + rr];
            bnv[ht][rr] = nb1[hbase + 16*ht + 4*g + rr];
        }

    {
        int m = t >> 2;
        int c0 = (t & 3) * 32;
        int row = n0 + m; if (row > N - 1) row = N - 1;
        const float* src = z + (size_t)row * 128 + c0;
#pragma unroll
        for (int q = 0; q < 4; ++q) {
            f32x4 a = *(const f32x4*)(src + 8*q);
            f32x4 b = *(const f32x4*)(src + 8*q + 4);
            *(bf16x8*)(z_lds + swz128(m, c0 + 8*q)) = cvt8(a, b);
        }
    }
    __syncthreads();

    const f32x4 vzero = {0.f, 0.f, 0.f, 0.f};
    f32x4 acc1[2][4], accz[2][4];
#pragma unroll
    for (int a = 0; a < 2; ++a)
#pragma unroll
        for (int b = 0; b < 4; ++b) { acc1[a][b] = vzero; accz[a][b] = vzero; }

#pragma unroll
    for (int kb = 0; kb < 4; ++kb) {
        bf16x8 bz[4];
#pragma unroll
        for (int mt = 0; mt < 4; ++mt)
            bz[mt] = *(const bf16x8*)(z_lds + swz128(16*mt + li, kb*32 + 8*g));
#pragma unroll
        for (int ht = 0; ht < 2; ++ht)
#pragma unroll
            for (int mt = 0; mt < 4; ++mt) {
                acc1[ht][mt] = MFMA(w1f[ht][kb], bz[mt], acc1[ht][mt]);
                accz[ht][mt] = MFMA(wzf[ht][kb], bz[mt], accz[ht][mt]);
            }
    }

#pragma unroll
    for (int ht = 0; ht < 2; ++ht)
#pragma unroll
        for (int mt = 0; mt < 4; ++mt) {
            int row = n0 + 16*mt + li;
            if (row < N) {
                f32x4 v;
#pragma unroll
                for (int rr = 0; rr < 4; ++rr) v[rr] = accz[ht][mt][rr] + bnv[ht][rr];
                *(f32x4*)(u1 + (size_t)row * 128 + hbase + 16*ht + 4*g) = v;
            }
        }

#pragma unroll
    for (int ht = 0; ht < 2; ++ht)
#pragma unroll
        for (int mt = 0; mt < 4; ++mt) {
            float v0 = fast_tanh(acc1[ht][mt][0] + b1v[ht][0]);
            float v1 = fast_tanh(acc1[ht][mt][1] + b1v[ht][1]);
            float v2 = fast_tanh(acc1[ht][mt][2] + b1v[ht][2]);
            float v3 = fast_tanh(acc1[ht][mt][3] + b1v[ht][3]);
            int m = 16*mt + li;
            int h = hbase + 16*ht + 4*g;
            st_pair(h1_lds, swz128(m, h),     v0, v1);
            st_pair(h1_lds, swz128(m, h + 2), v2, v3);
        }
    __syncthreads();

    f32x4 acc2[2][4];
#pragma unroll
    for (int a = 0; a < 2; ++a)
#pragma unroll
        for (int b = 0; b < 4; ++b) acc2[a][b] = vzero;

#pragma unroll
    for (int kb = 0; kb < 4; ++kb) {
        bf16x8 bh[4];
#pragma unroll
        for (int mt = 0; mt < 4; ++mt)
            bh[mt] = *(const bf16x8*)(h1_lds + swz128(16*mt + li, kb*32 + 8*g));
#pragma unroll
        for (int ht = 0; ht < 2; ++ht)
#pragma unroll
            for (int mt = 0; mt < 4; ++mt)
                acc2[ht][mt] = MFMA(w2f[ht][kb], bh[mt], acc2[ht][mt]);
    }
#pragma unroll
    for (int ht = 0; ht < 2; ++ht)
#pragma unroll
        for (int mt = 0; mt < 4; ++mt) {
            float v0 = fast_tanh(acc2[ht][mt][0] + b2v[ht][0]);
            float v1 = fast_tanh(acc2[ht][mt][1] + b2v[ht][1]);
            float v2 = fast_tanh(acc2[ht][mt][2] + b2v[ht][2]);
            float v3 = fast_tanh(acc2[ht][mt][3] + b2v[ht][3]);
            int row = n0 + 16*mt + li;
            if (row < N) {
                int h = hbase + 16*ht + 4*g;
                bf16* dst = feat + (size_t)row * 256 + h;
                bf16x2 p01 = {(bf16)v0, (bf16)v1};
                bf16x2 p23 = {(bf16)v2, (bf16)v3};
                *(bf16x2*)(dst)     = p01;
                *(bf16x2*)(dst + 2) = p23;
            }
        }
}

// ---------------------------------------------------------------------------
// Kernel C: dc = feat[N,256] @ ow^T + ob -> f32 out. 64 rows/block.
// ---------------------------------------------------------------------------
__global__ __launch_bounds__(256, 2) void out_kernel(
    const bf16* __restrict__ feat,
    const float* __restrict__ ow, const float* __restrict__ ob,
    float* __restrict__ out, int N)
{
    __shared__ char f_lds[64 * 512];

    const int t = threadIdx.x, wv = t >> 6, lane = t & 63, g = lane >> 4, li = lane & 15;
    const int cbase = wv * 16;
    const int n0 = blockIdx.x * 64;

    bf16x8 owf[8];
#pragma unroll
    for (int kb = 0; kb < 8; ++kb) {
        const float* p = ow + (size_t)(cbase + li) * 256 + kb*32 + 8*g;
        owf[kb] = cvt8(*(const f32x4*)p, *(const f32x4*)(p + 4));
    }
    float obv = ob[cbase + li];

    {
        int m = t >> 2;
        int c0 = (t & 3) * 64;
        int row = n0 + m; if (row > N - 1) row = N - 1;
        const bf16* src = feat + (size_t)row * 256 + c0;
#pragma unroll
        for (int q = 0; q < 8; ++q)
            *(bf16x8*)(f_lds + swz256(m, c0 + 8*q)) = *(const bf16x8*)(src + 8*q);
    }
    __syncthreads();

    const f32x4 vzero = {0.f, 0.f, 0.f, 0.f};
    f32x4 acc[4];
#pragma unroll
    for (int a = 0; a < 4; ++a) acc[a] = vzero;

#pragma unroll
    for (int kb = 0; kb < 8; ++kb) {
        bf16x8 af[4];
#pragma unroll
        for (int mt = 0; mt < 4; ++mt)
            af[mt] = *(const bf16x8*)(f_lds + swz256(16*mt + li, kb*32 + 8*g));
#pragma unroll
        for (int mt = 0; mt < 4; ++mt)
            acc[mt] = MFMA(af[mt], owf[kb], acc[mt]);
    }
#pragma unroll
    for (int mt = 0; mt < 4; ++mt)
#pragma unroll
        for (int rr = 0; rr < 4; ++rr) {
            int row = n0 + 16*mt + 4*g + rr;
            if (row < N) out[(size_t)row * 64 + cbase + li] = acc[mt][rr] + obv;
        }
}

// ---------------------------------------------------------------------------
extern "C" void kernel_launch(void* const* d_in, const int* in_sizes, int n_in,
                              void* d_out, int out_size, void* d_ws, size_t ws_size,
                              hipStream_t stream) {
    const float* z   = (const float*)d_in[0];
    const float* zn  = (const float*)d_in[1];
    const float* cw1 = (const float*)d_in[2];
    const float* cb1 = (const float*)d_in[3];
    const float* cw2 = (const float*)d_in[4];
    const float* cb2 = (const float*)d_in[5];
    const float* nw1 = (const float*)d_in[6];
    const float* nb1 = (const float*)d_in[7];
    const float* nw2 = (const float*)d_in[8];
    const float* nb2 = (const float*)d_in[9];
    const float* ow  = (const float*)d_in[10];
    const float* ob  = (const float*)d_in[11];
    float* out = (float*)d_out;

    const int N  = in_sizes[0] / 128;          // 20000
    const int NP = N / 2;                      // 10000 pairs
    const int nblk = (N + 63) / 64;            // 313

    char* ws = (char*)d_ws;
    bf16*  feat = (bf16*)ws;                                     // [N][256] bf16
    float* u1   = (float*)(ws + (size_t)N * 256 * sizeof(bf16)); // [N][128] f32

    (void)n_in; (void)out_size; (void)ws_size;

    cur_kernel<<<nblk, 256, 0, stream>>>(z, cw1, cb1, cw2, cb2, nw1, nb1, feat, u1, N);
    nbr_kernel<<<768, 256, 0, stream>>>(zn, u1, nw1, nw2, nb2, feat, NP);
    out_kernel<<<nblk, 256, 0, stream>>>(feat, ow, ob, out, N);
}